// Round 5
// baseline (445.469 us; speedup 1.0000x reference)
//
#include <hip/hip_runtime.h>

// ---------- types ----------
typedef __bf16 bf16_t;
typedef bf16_t bf16x8 __attribute__((ext_vector_type(8)));
typedef float f32x4 __attribute__((ext_vector_type(4)));
typedef unsigned short u16;
typedef u16 u16x8 __attribute__((ext_vector_type(8)));
typedef u16 u16x4 __attribute__((ext_vector_type(4)));

// ---------- model dims ----------
#define SEQ   2048
#define HID   2048
#define INTER 4096
#define NH    64
#define HD    64
#define CONVD 4352
#define DIN   8512
#define LDP   8576L   // proj leading dim (67*128)
#define CHNK  256
#define NC    8

__device__ __forceinline__ u16 f2bf(float f) {
  union { float f; unsigned u; } a; a.f = f;
  return (u16)((a.u + 0x7fffu + ((a.u >> 16) & 1u)) >> 16);
}
__device__ __forceinline__ float bf2f(u16 u) {
  union { unsigned u; float f; } a; a.u = ((unsigned)u) << 16;
  return a.f;
}

__device__ __forceinline__ void gl2lds16(const void* g, void* l) {
  auto gp = reinterpret_cast<__attribute__((address_space(1))) void*>(
      (unsigned long long)g);
  auto lp = reinterpret_cast<__attribute__((address_space(3))) void*>(
      (unsigned)(unsigned long long)l);
  __builtin_amdgcn_global_load_lds(gp, lp, 16, 0, 0);
}

// forced-register LDS vector read
__device__ __forceinline__ bf16x8 ds128(unsigned addr) {
  bf16x8 r;
  asm volatile("ds_read_b128 %0, %1" : "=v"(r) : "v"(addr));
  return r;
}

// ---------- fp32 -> bf16 flat convert (vectorized, n4 = n/4) ----------
__global__ __launch_bounds__(256) void cvt_bf16(const float* __restrict__ s,
                                                u16* __restrict__ d, int n4) {
  int i = blockIdx.x * 256 + threadIdx.x;
  if (i < n4) {
    f32x4 v = ((const f32x4*)s)[i];
    u16x4 r;
#pragma unroll
    for (int k = 0; k < 4; ++k) r[k] = f2bf(v[k]);
    ((u16x4*)d)[i] = r;
  }
}

// ---------- transpose + convert: src[R][Cc] fp32 -> dst[n][R] bf16 (zero-pad n>=Cc) ----------
__global__ void transpose_bf16(const float* __restrict__ src, u16* __restrict__ dst,
                               int R, int Cc) {
  __shared__ float t[32][33];
  int n0 = blockIdx.x * 32, k0 = blockIdx.y * 32;
  int tx = threadIdx.x, ty = threadIdx.y;
  for (int i = ty; i < 32; i += 8) {
    int n = n0 + tx;
    t[i][tx] = (n < Cc) ? src[(long)(k0 + i) * Cc + n] : 0.f;
  }
  __syncthreads();
  for (int i = ty; i < 32; i += 8)
    dst[(long)(n0 + i) * R + k0 + tx] = f2bf(t[tx][i]);
}

// ---------- zero the proj B/C/dt strip (cols 8192..8575) ----------
__global__ __launch_bounds__(256) void zero_strip(float* __restrict__ proj) {
  int g = blockIdx.x * 256 + threadIdx.x;   // 0 .. 2048*96-1
  int r = g / 96, c4 = g - r * 96;
  ((f32x4*)(proj + (long)r * LDP + 8192))[c4] = (f32x4){0.f, 0.f, 0.f, 0.f};
}

// ---------- bf16 MFMA GEMM: 128x128 tile, BK=64; AT=1 -> atomic accumulate ----------
template <int AT>
__global__ __launch_bounds__(256, 2) void gemm_bt(const u16* __restrict__ A,
                                                  const u16* __restrict__ Bt,
                                                  float* __restrict__ C,
                                                  int N, int lda, int Klen,
                                                  long zstride) {
  __shared__ __align__(16) u16 As[128 * 64];
  __shared__ __align__(16) u16 Bs[128 * 64];
  const int kz = blockIdx.z;
  A  += (long)kz * Klen;
  Bt += (long)kz * Klen;
  C  += (long)kz * zstride;
  const int nb = gridDim.x * gridDim.y;
  const int id = blockIdx.x + gridDim.x * blockIdx.y;
  const int s = (id & 7) * (nb >> 3) + (id >> 3);
  const long bm = s & 15;
  const long bn = s >> 4;

  const int tid = threadIdx.x;
  const int lane = tid & 63;
  const int w = tid >> 6;
  const int wm = w >> 1, wn = w & 1;

  f32x4 acc[4][4];
#pragma unroll
  for (int i = 0; i < 4; ++i)
#pragma unroll
    for (int j = 0; j < 4; ++j) acc[i][j] = (f32x4){0.f, 0.f, 0.f, 0.f};

  const int srr = lane >> 3;                 // sub-row 0..7
  const int sc8 = ((lane & 7) ^ srr) * 8;    // swizzled source chunk (elements)
  const u16* Agw = A + (bm * 128 + w * 8 + srr) * (long)lda + sc8;
  const u16* Bgw = Bt + (bn * 128 + w * 8 + srr) * (long)lda + sc8;
  u16* ldA = As + w * 512 + lane * 8;
  u16* ldB = Bs + w * 512 + lane * 8;
  const int fr = lane & 15, q = lane >> 4;
  const int fx = (fr & 7) << 3;

  for (int k0 = 0; k0 < Klen; k0 += 64) {
    __syncthreads();
#pragma unroll
    for (int t = 0; t < 4; ++t) {
      gl2lds16(Agw + k0 + (long)t * 32 * lda, ldA + t * 2048);
      gl2lds16(Bgw + k0 + (long)t * 32 * lda, ldB + t * 2048);
    }
    __builtin_amdgcn_s_waitcnt(0);
    __syncthreads();
#pragma unroll
    for (int ks = 0; ks < 2; ++ks) {
      bf16x8 af[4], bfv[4];
#pragma unroll
      for (int i = 0; i < 4; ++i)
        af[i] = *(const bf16x8*)(As + ((wm * 64 + i * 16 + fr) << 6) +
                                 ((((ks << 2) + q) << 3) ^ fx));
#pragma unroll
      for (int j = 0; j < 4; ++j)
        bfv[j] = *(const bf16x8*)(Bs + ((wn * 64 + j * 16 + fr) << 6) +
                                  ((((ks << 2) + q) << 3) ^ fx));
#pragma unroll
      for (int i = 0; i < 4; ++i)
#pragma unroll
        for (int j = 0; j < 4; ++j)
          acc[i][j] = __builtin_amdgcn_mfma_f32_16x16x32_bf16(af[i], bfv[j], acc[i][j], 0, 0, 0);
    }
  }
  const int cr = (lane >> 4) * 4;
  const int cc = lane & 15;
#pragma unroll
  for (int i = 0; i < 4; ++i)
#pragma unroll
    for (int j = 0; j < 4; ++j) {
      long r = bm * 128 + wm * 64 + i * 16 + cr;
      long cidx = bn * 128 + wn * 64 + j * 16 + cc;
      float* cp = C + r * (long)N + cidx;
#pragma unroll
      for (int t = 0; t < 4; ++t) {
        if (AT)
          unsafeAtomicAdd(&cp[(long)t * N], acc[i][j][t]);
        else
          cp[(long)t * N] = acc[i][j][t];
      }
    }
}

// ============================================================================
// 256x256-tile 8-phase bf16 MFMA GEMM (T2+T3+T4+T5), BK=64, 512 threads.
// Verified round-3 main loop (78 us in-proj).  AT=1 -> atomic epilogue.
// ============================================================================
#define MFMA16(ACC, AF, BF)                                                    \
  _Pragma("unroll") for (int i_ = 0; i_ < 4; ++i_)                             \
  _Pragma("unroll") for (int j_ = 0; j_ < 2; ++j_) {                           \
    ACC[i_][j_] = __builtin_amdgcn_mfma_f32_16x16x32_bf16(                     \
        AF[i_][0], BF[j_][0], ACC[i_][j_], 0, 0, 0);                           \
    ACC[i_][j_] = __builtin_amdgcn_mfma_f32_16x16x32_bf16(                     \
        AF[i_][1], BF[j_][1], ACC[i_][j_], 0, 0, 0);                           \
  }

#define LDAF(DST, SLOT)                                                        \
  {                                                                            \
    unsigned ab_ = (unsigned)(unsigned long long)(&Abuf[SLOT][0]);             \
    _Pragma("unroll") for (int i_ = 0; i_ < 4; ++i_) {                         \
      unsigned ro_ = ab_ + (((wm * 64 + i_ * 16 + fr) << 6) << 1);             \
      DST[i_][0] = ds128(ro_ + (ke0 << 1));                                    \
      DST[i_][1] = ds128(ro_ + (ke1 << 1));                                    \
    }                                                                          \
  }

#define LDBF(DST, SLOT)                                                        \
  {                                                                            \
    unsigned bb_ = (unsigned)(unsigned long long)(&Bbuf[SLOT][0]);             \
    _Pragma("unroll") for (int j_ = 0; j_ < 2; ++j_) {                         \
      unsigned ro_ = bb_ + (((wn * 32 + j_ * 16 + fr) << 6) << 1);             \
      DST[j_][0] = ds128(ro_ + (ke0 << 1));                                    \
      DST[j_][1] = ds128(ro_ + (ke1 << 1));                                    \
    }                                                                          \
  }

#define STAGE(G, HO, KO, SLOT, BUF)                                            \
  {                                                                            \
    const u16* g_ = (G) + (HO) + (KO);                                         \
    gl2lds16(g_ + off1, BUF[SLOT] + lo1);                                      \
    gl2lds16(g_ + off2, BUF[SLOT] + lo2);                                      \
  }

#define PH_FENCE()                                                             \
  asm volatile("s_waitcnt lgkmcnt(0)" ::: "memory");                           \
  __builtin_amdgcn_sched_barrier(0);

template <int AT>
__global__ __launch_bounds__(512, 2) void gemm256(const u16* __restrict__ A,
                                                  const u16* __restrict__ Bt,
                                                  float* __restrict__ C,
                                                  int N, int lda, int Klen,
                                                  long zstride) {
  __shared__ __align__(16) u16 Abuf[4][128 * 64];
  __shared__ __align__(16) u16 Bbuf[4][128 * 64];

  const int kz = blockIdx.z;
  A  += (long)kz * Klen;
  Bt += (long)kz * Klen;
  C  += (long)kz * zstride;

  // XCD-contiguous remap (nb % 8 == 0)
  const int nb = gridDim.x * gridDim.y;
  const int id = blockIdx.x + gridDim.x * blockIdx.y;
  const int s = (id & 7) * (nb >> 3) + (id >> 3);
  const long bm = s & 7;
  const long bn = s >> 3;

  const int tid = threadIdx.x;
  const int lane = tid & 63;
  const int w = tid >> 6;        // wave 0..7
  const int wm = w >> 2;         // 0..1
  const int wn = w & 3;          // 0..3
  const int fr = lane & 15, q = lane >> 4;
  const int ke0 = (q ^ (fr & 7)) << 3;         // swizzled k-chunk, ks=0
  const int ke1 = ((4 + q) ^ (fr & 7)) << 3;   // ks=1

  const int sr1 = (w << 4) + (lane >> 3);      // 0..127
  const int sr2 = sr1 + 8;
  const int kcp = lane & 7;
  const long off1 = (long)sr1 * lda + ((kcp ^ (sr1 & 7)) << 3);
  const long off2 = (long)sr2 * lda + ((kcp ^ (sr2 & 7)) << 3);
  const int lo1 = (w << 10) + (lane << 3);
  const int lo2 = lo1 + 512;
  const long h128 = 128L * lda;

  const u16* gA = A + bm * 256 * lda;
  const u16* gB = Bt + bn * 256 * lda;

  f32x4 acc00[4][2], acc01[4][2], acc10[4][2], acc11[4][2];
#pragma unroll
  for (int i = 0; i < 4; ++i)
#pragma unroll
    for (int j = 0; j < 2; ++j) {
      acc00[i][j] = (f32x4){0.f, 0.f, 0.f, 0.f};
      acc01[i][j] = (f32x4){0.f, 0.f, 0.f, 0.f};
      acc10[i][j] = (f32x4){0.f, 0.f, 0.f, 0.f};
      acc11[i][j] = (f32x4){0.f, 0.f, 0.f, 0.f};
    }

  const int NT = Klen >> 6;

  // ---- prologue: stage halves h0..h5 ----
  STAGE(gA, 0L, 0L, 0, Abuf);
  STAGE(gB, 0L, 0L, 0, Bbuf);
  STAGE(gB, h128, 0L, 1, Bbuf);
  STAGE(gA, h128, 0L, 1, Abuf);
  STAGE(gA, 0L, 64L, 2, Abuf);
  STAGE(gB, 0L, 64L, 2, Bbuf);
  asm volatile("s_waitcnt vmcnt(6)" ::: "memory");
  __builtin_amdgcn_s_barrier();

  for (int T = 0; T < NT; ++T) {
    const int t2 = (T << 1) & 3;
    const int t2p1 = (t2 + 1) & 3;
    const int t2p3 = (t2 + 3) & 3;
    const long kT1 = (long)(T + 1) << 6;
    const long kT2 = (long)(T + 2) << 6;
    const bool g1 = (T + 1 < NT), g2 = (T + 2 < NT);
    bf16x8 a0[4][2], a1[4][2], b0[2][2], b1[2][2];

    // ---- phase 1: (A0,B0); stage B1(T+1) ----
    LDAF(a0, t2);
    LDBF(b0, t2);
    if (g1) STAGE(gB, h128, kT1, t2p3, Bbuf);
    asm volatile("s_waitcnt lgkmcnt(8)" ::: "memory");
    __builtin_amdgcn_s_barrier();
    PH_FENCE();
    __builtin_amdgcn_s_setprio(1);
    MFMA16(acc00, a0, b0);
    __builtin_amdgcn_s_setprio(0);
    __builtin_amdgcn_s_barrier();

    // ---- phase 2: (A0,B1); stage A1(T+1); counted wait ----
    LDBF(b1, t2p1);
    if (g1) STAGE(gA, h128, kT1, t2p3, Abuf);
    __builtin_amdgcn_s_barrier();
    PH_FENCE();
    __builtin_amdgcn_s_setprio(1);
    MFMA16(acc01, a0, b1);
    __builtin_amdgcn_s_setprio(0);
    asm volatile("s_waitcnt vmcnt(6)" ::: "memory");
    __builtin_amdgcn_s_barrier();

    // ---- phase 3: (A1,B0); stage A0(T+2) ----
    LDAF(a1, t2p1);
    if (g2) STAGE(gA, 0L, kT2, t2, Abuf);
    __builtin_amdgcn_s_barrier();
    PH_FENCE();
    __builtin_amdgcn_s_setprio(1);
    MFMA16(acc10, a1, b0);
    __builtin_amdgcn_s_setprio(0);
    __builtin_amdgcn_s_barrier();

    // ---- phase 4: (A1,B1); stage B0(T+2); counted wait ----
    if (g2) STAGE(gB, 0L, kT2, t2, Bbuf);
    __builtin_amdgcn_s_barrier();
    PH_FENCE();
    __builtin_amdgcn_s_setprio(1);
    MFMA16(acc11, a1, b1);
    __builtin_amdgcn_s_setprio(0);
    if (T == NT - 2)
      asm volatile("s_waitcnt vmcnt(0)" ::: "memory");
    else
      asm volatile("s_waitcnt vmcnt(6)" ::: "memory");
    __builtin_amdgcn_s_barrier();
  }

  // ---- epilogue: C write (atomic when AT), col-guarded ----
  const int cr = (lane >> 4) << 2;
  const int cc = lane & 15;
  const long r0 = bm * 256 + wm * 64 + cr;
  const long c0 = bn * 256 + wn * 32 + cc;
#define CWRITE(ACC, QA, QB)                                                    \
  _Pragma("unroll") for (int i_ = 0; i_ < 4; ++i_)                             \
  _Pragma("unroll") for (int j_ = 0; j_ < 2; ++j_) {                           \
    long r_ = r0 + (QA)*128 + i_ * 16;                                         \
    long c_ = c0 + (QB)*128 + j_ * 16;                                         \
    if (c_ < N) {                                                              \
      float* cp_ = C + r_ * (long)N + c_;                                      \
      _Pragma("unroll") for (int t_ = 0; t_ < 4; ++t_) {                       \
        if (AT)                                                                \
          unsafeAtomicAdd(&cp_[(long)t_ * N], ACC[i_][j_][t_]);                \
        else                                                                   \
          cp_[(long)t_ * N] = ACC[i_][j_][t_];                                 \
      }                                                                        \
    }                                                                          \
  }
  CWRITE(acc00, 0, 0)
  CWRITE(acc01, 0, 1)
  CWRITE(acc10, 1, 0)
  CWRITE(acc11, 1, 1)
#undef CWRITE
}

// ---------- fused depthwise conv (K=4) + SiLU -> xbf AND xT (transposed) ----------
__global__ __launch_bounds__(256) void conv_silu_t(const float* __restrict__ proj,
                                                   const float* __restrict__ cw,
                                                   const float* __restrict__ cb,
                                                   u16* __restrict__ xbf,
                                                   u16* __restrict__ xT) {
  __shared__ float ld[35][33];
  __shared__ u16 tt[32][34];
  const int c0 = blockIdx.x * 32, t0 = blockIdx.y * 32;
  const int tx = threadIdx.x & 31, ty = threadIdx.x >> 5;
  for (int i = ty; i < 35; i += 8) {
    int t = t0 - 3 + i;
    ld[i][tx] = (t >= 0) ? proj[(long)t * LDP + INTER + c0 + tx] : 0.f;
  }
  const int c = c0 + tx;
  const float w0 = cw[c * 4 + 0], w1 = cw[c * 4 + 1], w2 = cw[c * 4 + 2],
              w3 = cw[c * 4 + 3], bias = cb[c];
  __syncthreads();
  for (int i = ty; i < 32; i += 8) {
    float a = bias + w0 * ld[i][tx] + w1 * ld[i + 1][tx] + w2 * ld[i + 2][tx] +
              w3 * ld[i + 3][tx];
    u16 v = f2bf(a / (1.f + __expf(-a)));
    xbf[(long)(t0 + i) * CONVD + c] = v;
    tt[i][tx] = v;
  }
  __syncthreads();
  if (c0 < 4224) {   // x + B + C regions get transposed
    for (int i = ty; i < 32; i += 8)
      xT[(long)(c0 + i) * 2048 + t0 + tx] = tt[tx][i];
  }
}

// ---------- dt softplus + per-chunk cumsum (Hillis-Steele), [h][t] layout ----------
__global__ __launch_bounds__(256) void dt_cumsum(const float* __restrict__ proj,
                                                 const float* __restrict__ dtb,
                                                 const float* __restrict__ A,
                                                 float* __restrict__ dt2,
                                                 float* __restrict__ cA2) {
  __shared__ float sc[256];
  int c = blockIdx.x, h = blockIdx.y, l = threadIdx.x;
  float v = proj[(long)(c * 256 + l) * LDP + 8448 + h] + dtb[h];
  float sp = (v > 20.f) ? v : log1pf(__expf(v));
  dt2[h * 2048 + c * 256 + l] = sp;
  sc[l] = sp * A[h];
  __syncthreads();
  for (int off = 1; off < 256; off <<= 1) {
    float t = (l >= off) ? sc[l - off] : 0.f;
    __syncthreads();
    sc[l] += t;
    __syncthreads();
  }
  cA2[h * 2048 + c * 256 + l] = sc[l];
}

// ---------- CB[c][l][s] = C[l,:].B[s,:] via MFMA, per-chunk strided GEMM ----------
__global__ __launch_bounds__(256, 2) void cb_gemm(const u16* __restrict__ xbf,
                                                  float* __restrict__ CB) {
  __shared__ __align__(16) u16 As[128 * 32];
  __shared__ __align__(16) u16 Bs[128 * 32];
  const int tid = threadIdx.x;
  const int lane = tid & 63;
  const int w = tid >> 6;
  const int wm = w >> 1, wn = w & 1;
  const int bm = blockIdx.y, bn = blockIdx.x, c = blockIdx.z;

  f32x4 acc[4][4];
#pragma unroll
  for (int i = 0; i < 4; ++i)
#pragma unroll
    for (int j = 0; j < 4; ++j) acc[i][j] = (f32x4){0.f, 0.f, 0.f, 0.f};

  const int sr = w * 32 + (lane >> 2);
  const int sc = ((lane & 3) ^ ((lane >> 2) & 3)) * 8;
  const u16* Ag = xbf + (long)(c * 256 + bm * 128) * CONVD + 4224;  // C region
  const u16* Bg = xbf + (long)(c * 256 + bn * 128) * CONVD + 4096;  // B region
  u16* lA0 = As + w * 1024 + lane * 8;
  u16* lA1 = As + w * 1024 + 512 + lane * 8;
  u16* lB0 = Bs + w * 1024 + lane * 8;
  u16* lB1 = Bs + w * 1024 + 512 + lane * 8;
  const int fr = lane & 15, q = lane >> 4;
  const int pc = ((q ^ (fr & 3)) << 3);

  for (int k0 = 0; k0 < 128; k0 += 32) {
    __syncthreads();
    const u16* a0 = Ag + (long)sr * CONVD + k0 + sc;
    const u16* b0 = Bg + (long)sr * CONVD + k0 + sc;
    gl2lds16(a0, lA0);
    gl2lds16(a0 + 16L * CONVD, lA1);
    gl2lds16(b0, lB0);
    gl2lds16(b0 + 16L * CONVD, lB1);
    __builtin_amdgcn_s_waitcnt(0);
    __syncthreads();
    bf16x8 af[4], bfv[4];
#pragma unroll
    for (int i = 0; i < 4; ++i)
      af[i] = *(const bf16x8*)(As + ((wm * 64 + i * 16 + fr) << 5) + pc);
#pragma unroll
    for (int j = 0; j < 4; ++j)
      bfv[j] = *(const bf16x8*)(Bs + ((wn * 64 + j * 16 + fr) << 5) + pc);
#pragma unroll
    for (int i = 0; i < 4; ++i)
#pragma unroll
      for (int j = 0; j < 4; ++j)
        acc[i][j] = __builtin_amdgcn_mfma_f32_16x16x32_bf16(af[i], bfv[j], acc[i][j], 0, 0, 0);
  }
  const int cr = (lane >> 4) * 4;
  const int cc = lane & 15;
  float* Cc = CB + (long)c * 65536;
#pragma unroll
  for (int i = 0; i < 4; ++i)
#pragma unroll
    for (int j = 0; j < 4; ++j) {
      int r = bm * 128 + wm * 64 + i * 16 + cr;
      int cidx = bn * 128 + wn * 64 + j * 16 + cc;
      float* cp = Cc + (long)r * 256 + cidx;
#pragma unroll
      for (int t = 0; t < 4; ++t) cp[t * 256] = acc[i][j][t];
    }
}

// ---------- states via MFMA: stT[n][p] = sum_l (B[l][n]*wl[l]) * x[l][p] ----------
#define LDM 72
__global__ __launch_bounds__(256) void states_kernel(const u16* __restrict__ xT,
                                                     const float* __restrict__ dt2,
                                                     const float* __restrict__ cA2,
                                                     float* __restrict__ stT) {
  __shared__ __align__(16) u16 Ms[128 * LDM];  // Bw [n][l_local]
  __shared__ __align__(16) u16 Xs[64 * LDM];   // x  [p][l_local]
  __shared__ float wl[256];
  const int c = blockIdx.x, h = blockIdx.y;
  const int tid = threadIdx.x;
  const int lane = tid & 63, w = tid >> 6;
  const int fr = lane & 15, q = lane >> 4;
  {
    float calast = cA2[h * 2048 + c * 256 + 255];
    float ca = cA2[h * 2048 + c * 256 + tid];
    wl[tid] = __expf(calast - ca) * dt2[h * 2048 + c * 256 + tid];
  }
  f32x4 acc[2][4];
#pragma unroll
  for (int i = 0; i < 2; ++i)
#pragma unroll
    for (int j = 0; j < 4; ++j) acc[i][j] = (f32x4){0.f, 0.f, 0.f, 0.f};

  const int lc8 = (tid & 7) * 8;
  const int rn = tid >> 3;   // 0..31
  __syncthreads();

  for (int kt = 0; kt < 4; ++kt) {
    __syncthreads();
#pragma unroll
    for (int r = 0; r < 4; ++r) {
      int n = rn + 32 * r;
      u16x8 raw = *(const u16x8*)(xT + (long)(4096 + n) * 2048 + c * 256 + kt * 64 + lc8);
      union { u16 u[8]; bf16x8 v; } pk;
#pragma unroll
      for (int u = 0; u < 8; ++u)
        pk.u[u] = f2bf(bf2f(raw[u]) * wl[kt * 64 + lc8 + u]);
      *(bf16x8*)(Ms + n * LDM + lc8) = pk.v;
    }
#pragma unroll
    for (int r = 0; r < 2; ++r) {
      int p = rn + 32 * r;
      *(bf16x8*)(Xs + p * LDM + lc8) =
          *(const bf16x8*)(xT + (long)(h * 64 + p) * 2048 + c * 256 + kt * 64 + lc8);
    }
    __syncthreads();
#pragma unroll
    for (int ks = 0; ks < 64; ks += 32) {
      bf16x8 af[2], xf[4];
#pragma unroll
      for (int i = 0; i < 2; ++i)
        af[i] = *(const bf16x8*)(Ms + (w * 32 + i * 16 + fr) * LDM + ks + q * 8);
#pragma unroll
      for (int j = 0; j < 4; ++j)
        xf[j] = *(const bf16x8*)(Xs + (j * 16 + fr) * LDM + ks + q * 8);
#pragma unroll
      for (int i = 0; i < 2; ++i)
#pragma unroll
        for (int j = 0; j < 4; ++j)
          acc[i][j] = __builtin_amdgcn_mfma_f32_16x16x32_bf16(af[i], xf[j], acc[i][j], 0, 0, 0);
    }
  }
  const int cr = (lane >> 4) * 4;
  const int cc = lane & 15;
  float* outp = stT + (long)(c * 64 + h) * 8192;
#pragma unroll
  for (int i = 0; i < 2; ++i)
#pragma unroll
    for (int j = 0; j < 4; ++j) {
      int n = w * 32 + i * 16 + cr;
      int p = j * 16 + cc;
#pragma unroll
      for (int t = 0; t < 4; ++t) outp[(n + t) * 64 + p] = acc[i][j][t];
    }
}

// ---------- 8-chunk inter-chunk scan ----------
__global__ __launch_bounds__(256) void scan_kernel(const float* __restrict__ stT,
                                                   const float* __restrict__ cA2,
                                                   float* __restrict__ prevT) {
  int id = blockIdx.x * 256 + threadIdx.x;   // h*8192 + n*64 + p
  int h = id >> 13;
  float acc = 0.f;
#pragma unroll
  for (int c = 0; c < NC; ++c) {
    prevT[(long)c * 524288 + id] = acc;
    float cd = __expf(cA2[h * 2048 + c * 256 + 255]);
    acc = acc * cd + stT[(long)c * 524288 + id];
  }
}

// ---------- intra+inter SSM output via bf16 MFMA ----------
__global__ __launch_bounds__(256) void ssm_y_kernel(const u16* __restrict__ xbf,
                                                    const u16* __restrict__ xT,
                                                    const float* __restrict__ dt2,
                                                    const float* __restrict__ cA2,
                                                    const float* __restrict__ CB,
                                                    const float* __restrict__ prevT,
                                                    const float* __restrict__ Dp,
                                                    u16* __restrict__ Y) {
  __shared__ __align__(16) u16 Ms[256 * LDM];
  __shared__ __align__(16) u16 Xt[64 * LDM];
  __shared__ float cas[256];
  __shared__ float dts[256];
  const int c = blockIdx.x, h = blockIdx.y;
  const int tid = threadIdx.x;
  const int lane = tid & 63;
  const int w = tid >> 6;
  const int fr = lane & 15, q = lane >> 4;

  cas[tid] = cA2[h * 2048 + c * 256 + tid];
  dts[tid] = dt2[h * 2048 + c * 256 + tid];

  f32x4 acc[4][4];
#pragma unroll
  for (int i = 0; i < 4; ++i)
#pragma unroll
    for (int j = 0; j < 4; ++j) acc[i][j] = (f32x4){0.f, 0.f, 0.f, 0.f};

  const int sg = (tid & 7) * 8;
  const int lb = tid >> 3;
  const int xp = tid & 63;
  const int xq = tid >> 6;

  __syncthreads();

  for (int kt = 0; kt < 6; ++kt) {
    __syncthreads();
    if (kt < 4) {
      const int s0 = kt * 64;
      f32x4 e0 = *(const f32x4*)&cas[s0 + sg];
      f32x4 e1 = *(const f32x4*)&cas[s0 + sg + 4];
      f32x4 d0 = *(const f32x4*)&dts[s0 + sg];
      f32x4 d1 = *(const f32x4*)&dts[s0 + sg + 4];
#pragma unroll
      for (int k = 0; k < 8; ++k) {
        const int l = lb + 32 * k;
        const float cal = cas[l];
        const float* cb = CB + (long)c * 65536 + (long)l * 256 + s0 + sg;
        f32x4 c0 = *(const f32x4*)cb;
        f32x4 c1 = *(const f32x4*)(cb + 4);
        union { u16 u[8]; bf16x8 v; } pk;
#pragma unroll
        for (int u = 0; u < 8; ++u) {
          int s = s0 + sg + u;
          float cv = (u < 4) ? c0[u] : c1[u - 4];
          float cs = (u < 4) ? e0[u] : e1[u - 4];
          float dv = (u < 4) ? d0[u] : d1[u - 4];
          float m = (s <= l) ? cv * __expf(cal - cs) * dv : 0.f;
          pk.u[u] = f2bf(m);
        }
        *(bf16x8*)(Ms + l * LDM + sg) = pk.v;
      }
#pragma unroll
      for (int r = 0; r < 2; ++r) {
        int p = (tid >> 3) + 32 * r;
        *(bf16x8*)(Xt + p * LDM + sg) =
            *(const bf16x8*)(xT + (long)(h * 64 + p) * 2048 + c * 256 + s0 + sg);
      }
    } else {
      const int n0 = (kt - 4) * 64;
#pragma unroll
      for (int k = 0; k < 8; ++k) {
        const int l = lb + 32 * k;
        const float ea = __expf(cas[l]);
        u16x8 raw = *(const u16x8*)(xbf + (long)(c * 256 + l) * CONVD + 4224 + n0 + sg);
        union { u16 u[8]; bf16x8 v; } pk;
#pragma unroll
        for (int u = 0; u < 8; ++u) pk.u[u] = f2bf(ea * bf2f(raw[u]));
        *(bf16x8*)(Ms + l * LDM + sg) = pk.v;
      }
      const float* pT = prevT + (long)(c * 64 + h) * 8192;
#pragma unroll
      for (int half = 0; half < 2; ++half) {
        const int nb2 = xq * 16 + half * 8;
        union { u16 u[8]; bf16x8 v; } pk;
#pragma unroll
        for (int u = 0; u < 8; ++u) pk.u[u] = f2bf(pT[(n0 + nb2 + u) * 64 + xp]);
        *(bf16x8*)(Xt + xp * LDM + nb2) = pk.v;
      }
    }
    __syncthreads();
#pragma unroll
    for (int ks = 0; ks < 64; ks += 32) {
      bf16x8 af[4], bfv[4];
#pragma unroll
      for (int i = 0; i < 4; ++i)
        af[i] = *(const bf16x8*)(Ms + (w * 64 + i * 16 + fr) * LDM + ks + q * 8);
#pragma unroll
      for (int j = 0; j < 4; ++j)
        bfv[j] = *(const bf16x8*)(Xt + (j * 16 + fr) * LDM + ks + q * 8);
#pragma unroll
      for (int i = 0; i < 4; ++i)
#pragma unroll
        for (int j = 0; j < 4; ++j)
          acc[i][j] = __builtin_amdgcn_mfma_f32_16x16x32_bf16(af[i], bfv[j], acc[i][j], 0, 0, 0);
    }
  }

  const int cr = (lane >> 4) * 4;
  const int cc = lane & 15;
  const float dh = Dp[h];
#pragma unroll
  for (int i = 0; i < 4; ++i)
#pragma unroll
    for (int j = 0; j < 4; ++j) {
      const int p = j * 16 + cc;
#pragma unroll
      for (int t = 0; t < 4; ++t) {
        const int row = w * 64 + i * 16 + cr + t;
        const float xv = bf2f(xbf[(long)(c * 256 + row) * CONVD + h * 64 + p]);
        Y[(long)(c * 256 + row) * 4096 + h * 64 + p] = f2bf(acc[i][j][t] + dh * xv);
      }
    }
}

// ---------- gated RMSNorm (Y in bf16) -> bf16 z ----------
__global__ __launch_bounds__(256) void rmsnorm_kernel(const u16* __restrict__ Y,
                                                      const float* __restrict__ proj,
                                                      const float* __restrict__ nw,
                                                      u16* __restrict__ zbf) {
  __shared__ float red[256];
  int t = blockIdx.x, tid = threadIdx.x;
  const u16* y = Y + (long)t * 4096;
  const float* g = proj + (long)t * LDP;
  float zv[16];
  float s = 0.f;
#pragma unroll
  for (int k = 0; k < 16; ++k) {
    int i = tid + k * 256;
    float gv = g[i];
    float z = bf2f(y[i]) * (gv / (1.f + __expf(-gv)));
    zv[k] = z;
    s += z * z;
  }
  red[tid] = s;
  __syncthreads();
  if (tid < 128) red[tid] += red[tid + 128];
  __syncthreads();
  if (tid < 64) {
    float v = red[tid] + red[tid + 64];
    v += __shfl_down(v, 32);
    v += __shfl_down(v, 16);
    v += __shfl_down(v, 8);
    v += __shfl_down(v, 4);
    v += __shfl_down(v, 2);
    v += __shfl_down(v, 1);
    if (tid == 0) red[0] = v;
  }
  __syncthreads();
  float scale = rsqrtf(red[0] * (1.f / 4096.f) + 1e-5f);
#pragma unroll
  for (int k = 0; k < 16; ++k) {
    int i = tid + k * 256;
    zbf[(long)t * 4096 + i] = f2bf(zv[k] * scale * nw[i]);
  }
}

// ---------- launch ----------
extern "C" void kernel_launch(void* const* d_in, const int* in_sizes, int n_in,
                              void* d_out, int out_size, void* d_ws, size_t ws_size,
                              hipStream_t stream) {
  const float* hidden = (const float*)d_in[0];
  const float* Win    = (const float*)d_in[1];
  const float* convw  = (const float*)d_in[2];
  const float* convb  = (const float*)d_in[3];
  const float* dtb    = (const float*)d_in[4];
  const float* Ap     = (const float*)d_in[5];
  const float* Dp     = (const float*)d_in[6];
  const float* nw     = (const float*)d_in[7];
  const float* Wout   = (const float*)d_in[8];
  float* out = (float*)d_out;
  char* ws = (char*)d_ws;

  // workspace layout (bytes) — identical footprint to the verified layout.
  u16*   hb    = (u16*)(ws + 0);            //  8,388,608
  u16*   WinT  = (u16*)(ws + 8388608L);     // 35,127,296  [8576][2048] bf16
  float* proj  = (float*)(ws + 43515904L);  // 70,254,592  [2048][8576] f32
  u16*   WoutT = (u16*)(ws + 113770496L);   // 16,777,216  [2048][4096] bf16
  u16*   xbf   = (u16*)(ws + 130547712L);   // 17,825,792  [2048][4352] bf16
  u16*   xT    = (u16*)(ws + 148373504L);   // 17,301,504  [4224][2048] bf16
  float* dt2   = (float*)(ws + 165675008L); //    524,288  [64][2048]
  float* cA2   = (float*)(ws + 166199296L); //    524,288  [64][2048]
  float* CBv   = (float*)(ws + 166723584L); //  2,097,152  [8][256][256]
  float* stT   = (float*)(ws + 168820736L); // 16,777,216  [8][64][128][64]
  float* prevT = (float*)(ws + 185597952L); // 16,777,216
  u16*   zbf   = (u16*)(ws + 202375168L);   // 16,777,216  [2048][4096] bf16
  u16*   Y     = (u16*)(ws + 0);            // 16,777,216  bf16 (overlay hb+WinT, dead)

  // zero the output accumulator (out-proj split-K atomics land here)
  hipMemsetAsync(out, 0, (size_t)out_size, stream);
  cvt_bf16<<<4096, 256, 0, stream>>>(hidden, hb, 1048576);
  transpose_bf16<<<dim3(268, 64), dim3(32, 8), 0, stream>>>(Win, WinT, 2048, 8512);
  transpose_bf16<<<dim3(64, 128), dim3(32, 8), 0, stream>>>(Wout, WoutT, 4096, 2048);
  zero_strip<<<768, 256, 0, stream>>>(proj);
  // in-proj main: gate+x cols [0,8192) = 8x32 tiles of 256^2, 256 blocks
  gemm256<0><<<dim3(32, 8, 1), 512, 0, stream>>>(hb, WinT, proj, 8576, 2048, 2048, 0L);
  // in-proj strip: B/C/dt cols [8192,8576), split-K4 atomic into proj
  gemm_bt<1><<<dim3(3, 16, 4), 256, 0, stream>>>(hb, WinT + 8192L * 2048, proj + 8192,
                                                 8576, 2048, 512, 0L);
  conv_silu_t<<<dim3(136, 64), 256, 0, stream>>>(proj, convw, convb, xbf, xT);
  dt_cumsum<<<dim3(8, 64), 256, 0, stream>>>(proj, dtb, Ap, dt2, cA2);
  cb_gemm<<<dim3(2, 2, 8), 256, 0, stream>>>(xbf, CBv);
  states_kernel<<<dim3(8, 64), 256, 0, stream>>>(xT, dt2, cA2, stT);
  scan_kernel<<<2048, 256, 0, stream>>>(stT, cA2, prevT);
  ssm_y_kernel<<<dim3(8, 64), 256, 0, stream>>>(xbf, xT, dt2, cA2, CBv, prevT, Dp, Y);
  rmsnorm_kernel<<<2048, 256, 0, stream>>>(Y, proj, nw, zbf);
  // out-proj: 8x8 tiles x split-K4 = 256 blocks, atomic accumulate into out
  gemm256<1><<<dim3(8, 8, 4), 512, 0, stream>>>(zbf, WoutT, out, 2048, 4096, 1024, 0L);
}

// Round 6
// 407.664 us; speedup vs baseline: 1.0927x; 1.0927x over previous
//
#include <hip/hip_runtime.h>

// ---------- types ----------
typedef __bf16 bf16_t;
typedef bf16_t bf16x8 __attribute__((ext_vector_type(8)));
typedef float f32x4 __attribute__((ext_vector_type(4)));
typedef unsigned short u16;
typedef u16 u16x8 __attribute__((ext_vector_type(8)));
typedef u16 u16x4 __attribute__((ext_vector_type(4)));

// ---------- model dims ----------
#define SEQ   2048
#define HID   2048
#define INTER 4096
#define NH    64
#define HD    64
#define CONVD 4352
#define DIN   8512
#define LDP   8576L   // proj leading dim (67*128)
#define CHNK  256
#define NC    8

__device__ __forceinline__ u16 f2bf(float f) {
  union { float f; unsigned u; } a; a.f = f;
  return (u16)((a.u + 0x7fffu + ((a.u >> 16) & 1u)) >> 16);
}
__device__ __forceinline__ float bf2f(u16 u) {
  union { unsigned u; float f; } a; a.u = ((unsigned)u) << 16;
  return a.f;
}

__device__ __forceinline__ void gl2lds16(const void* g, void* l) {
  auto gp = reinterpret_cast<__attribute__((address_space(1))) void*>(
      (unsigned long long)g);
  auto lp = reinterpret_cast<__attribute__((address_space(3))) void*>(
      (unsigned)(unsigned long long)l);
  __builtin_amdgcn_global_load_lds(gp, lp, 16, 0, 0);
}

// forced-register LDS vector read
__device__ __forceinline__ bf16x8 ds128(unsigned addr) {
  bf16x8 r;
  asm volatile("ds_read_b128 %0, %1" : "=v"(r) : "v"(addr));
  return r;
}

// ---------- fp32 -> bf16 flat convert (vectorized, n4 = n/4) ----------
__global__ __launch_bounds__(256) void cvt_bf16(const float* __restrict__ s,
                                                u16* __restrict__ d, int n4) {
  int i = blockIdx.x * 256 + threadIdx.x;
  if (i < n4) {
    f32x4 v = ((const f32x4*)s)[i];
    u16x4 r;
#pragma unroll
    for (int k = 0; k < 4; ++k) r[k] = f2bf(v[k]);
    ((u16x4*)d)[i] = r;
  }
}

// ---------- transpose + convert: src[R][Cc] fp32 -> dst[n][R] bf16 (zero-pad n>=Cc) ----------
__global__ void transpose_bf16(const float* __restrict__ src, u16* __restrict__ dst,
                               int R, int Cc) {
  __shared__ float t[32][33];
  int n0 = blockIdx.x * 32, k0 = blockIdx.y * 32;
  int tx = threadIdx.x, ty = threadIdx.y;
  for (int i = ty; i < 32; i += 8) {
    int n = n0 + tx;
    t[i][tx] = (n < Cc) ? src[(long)(k0 + i) * Cc + n] : 0.f;
  }
  __syncthreads();
  for (int i = ty; i < 32; i += 8)
    dst[(long)(n0 + i) * R + k0 + tx] = f2bf(t[tx][i]);
}

// ---------- bf16 MFMA GEMM: 128x128 tile, BK=64 (used for the 384-col strip) ----------
__global__ __launch_bounds__(256, 2) void gemm_bt(const u16* __restrict__ A,
                                                  const u16* __restrict__ Bt,
                                                  float* __restrict__ C,
                                                  int N, int lda, int Klen,
                                                  long zstride) {
  __shared__ __align__(16) u16 As[128 * 64];
  __shared__ __align__(16) u16 Bs[128 * 64];
  const int kz = blockIdx.z;
  A  += (long)kz * Klen;
  Bt += (long)kz * Klen;
  C  += (long)kz * zstride;
  const int nb = gridDim.x * gridDim.y;
  const int id = blockIdx.x + gridDim.x * blockIdx.y;
  const int s = (id & 7) * (nb >> 3) + (id >> 3);
  const long bm = s & 15;
  const long bn = s >> 4;

  const int tid = threadIdx.x;
  const int lane = tid & 63;
  const int w = tid >> 6;
  const int wm = w >> 1, wn = w & 1;

  f32x4 acc[4][4];
#pragma unroll
  for (int i = 0; i < 4; ++i)
#pragma unroll
    for (int j = 0; j < 4; ++j) acc[i][j] = (f32x4){0.f, 0.f, 0.f, 0.f};

  const int srr = lane >> 3;                 // sub-row 0..7
  const int sc8 = ((lane & 7) ^ srr) * 8;    // swizzled source chunk (elements)
  const u16* Agw = A + (bm * 128 + w * 8 + srr) * (long)lda + sc8;
  const u16* Bgw = Bt + (bn * 128 + w * 8 + srr) * (long)lda + sc8;
  u16* ldA = As + w * 512 + lane * 8;
  u16* ldB = Bs + w * 512 + lane * 8;
  const int fr = lane & 15, q = lane >> 4;
  const int fx = (fr & 7) << 3;

  for (int k0 = 0; k0 < Klen; k0 += 64) {
    __syncthreads();
#pragma unroll
    for (int t = 0; t < 4; ++t) {
      gl2lds16(Agw + k0 + (long)t * 32 * lda, ldA + t * 2048);
      gl2lds16(Bgw + k0 + (long)t * 32 * lda, ldB + t * 2048);
    }
    __builtin_amdgcn_s_waitcnt(0);
    __syncthreads();
#pragma unroll
    for (int ks = 0; ks < 2; ++ks) {
      bf16x8 af[4], bfv[4];
#pragma unroll
      for (int i = 0; i < 4; ++i)
        af[i] = *(const bf16x8*)(As + ((wm * 64 + i * 16 + fr) << 6) +
                                 ((((ks << 2) + q) << 3) ^ fx));
#pragma unroll
      for (int j = 0; j < 4; ++j)
        bfv[j] = *(const bf16x8*)(Bs + ((wn * 64 + j * 16 + fr) << 6) +
                                  ((((ks << 2) + q) << 3) ^ fx));
#pragma unroll
      for (int i = 0; i < 4; ++i)
#pragma unroll
        for (int j = 0; j < 4; ++j)
          acc[i][j] = __builtin_amdgcn_mfma_f32_16x16x32_bf16(af[i], bfv[j], acc[i][j], 0, 0, 0);
    }
  }
  const int cr = (lane >> 4) * 4;
  const int cc = lane & 15;
#pragma unroll
  for (int i = 0; i < 4; ++i)
#pragma unroll
    for (int j = 0; j < 4; ++j) {
      long r = bm * 128 + wm * 64 + i * 16 + cr;
      long cidx = bn * 128 + wn * 64 + j * 16 + cc;
      float* cp = C + r * (long)N + cidx;
#pragma unroll
      for (int t = 0; t < 4; ++t) cp[(long)t * N] = acc[i][j][t];
    }
}

// ============================================================================
// 256x256-tile 8-phase bf16 MFMA GEMM, BK=64, 512 threads.  v3 schedule:
// UNIFORM 2-tile lookahead with ONE counted wait per K-tile (m201 discipline).
// Tile T stages: ph2: A0(T+2); ph3: B0(T+2); ph4: B1(T+2)+A1(T+2).
// Single s_waitcnt vmcnt(8) at ph4 (leaves exactly tile-T's 8 staged loads
// outstanding -> all four halves of T+1, issued during T-1, are landed at
// entry to T+1).  Overwrite safety: each stage hits the slot whose last
// ds_read completed >=1 barrier earlier (A0 read ph1 -> staged ph2; B0 ph1 ->
// ph3; B1 ph2 -> ph4; A1 ph3 -> ph4).  Tail: vmcnt(0) once staging stops.
// ============================================================================
#define MFMA16(ACC, AF, BF)                                                    \
  _Pragma("unroll") for (int i_ = 0; i_ < 4; ++i_)                             \
  _Pragma("unroll") for (int j_ = 0; j_ < 2; ++j_) {                           \
    ACC[i_][j_] = __builtin_amdgcn_mfma_f32_16x16x32_bf16(                     \
        AF[i_][0], BF[j_][0], ACC[i_][j_], 0, 0, 0);                           \
    ACC[i_][j_] = __builtin_amdgcn_mfma_f32_16x16x32_bf16(                     \
        AF[i_][1], BF[j_][1], ACC[i_][j_], 0, 0, 0);                           \
  }

#define LDAF(DST, SLOT)                                                        \
  {                                                                            \
    unsigned ab_ = (unsigned)(unsigned long long)(&Abuf[SLOT][0]);             \
    _Pragma("unroll") for (int i_ = 0; i_ < 4; ++i_) {                         \
      unsigned ro_ = ab_ + (((wm * 64 + i_ * 16 + fr) << 6) << 1);             \
      DST[i_][0] = ds128(ro_ + (ke0 << 1));                                    \
      DST[i_][1] = ds128(ro_ + (ke1 << 1));                                    \
    }                                                                          \
  }

#define LDBF(DST, SLOT)                                                        \
  {                                                                            \
    unsigned bb_ = (unsigned)(unsigned long long)(&Bbuf[SLOT][0]);             \
    _Pragma("unroll") for (int j_ = 0; j_ < 2; ++j_) {                         \
      unsigned ro_ = bb_ + (((wn * 32 + j_ * 16 + fr) << 6) << 1);             \
      DST[j_][0] = ds128(ro_ + (ke0 << 1));                                    \
      DST[j_][1] = ds128(ro_ + (ke1 << 1));                                    \
    }                                                                          \
  }

#define STAGE(G, HO, KO, SLOT, BUF)                                            \
  {                                                                            \
    const u16* g_ = (G) + (HO) + (KO);                                         \
    gl2lds16(g_ + off1, BUF[SLOT] + lo1);                                      \
    gl2lds16(g_ + off2, BUF[SLOT] + lo2);                                      \
  }

#define PH_FENCE()                                                             \
  asm volatile("s_waitcnt lgkmcnt(0)" ::: "memory");                           \
  __builtin_amdgcn_sched_barrier(0);

__global__ __launch_bounds__(512, 2) void gemm256(const u16* __restrict__ A,
                                                  const u16* __restrict__ Bt,
                                                  float* __restrict__ C,
                                                  int N, int lda, int Klen,
                                                  long zstride) {
  __shared__ __align__(16) u16 Abuf[4][128 * 64];
  __shared__ __align__(16) u16 Bbuf[4][128 * 64];

  const int kz = blockIdx.z;
  A  += (long)kz * Klen;
  Bt += (long)kz * Klen;
  C  += (long)kz * zstride;

  // XCD-contiguous remap (nb % 8 == 0)
  const int nb = gridDim.x * gridDim.y;
  const int id = blockIdx.x + gridDim.x * blockIdx.y;
  const int s = (id & 7) * (nb >> 3) + (id >> 3);
  const long bm = s & 7;
  const long bn = s >> 3;

  const int tid = threadIdx.x;
  const int lane = tid & 63;
  const int w = tid >> 6;        // wave 0..7
  const int wm = w >> 2;         // 0..1
  const int wn = w & 3;          // 0..3
  const int fr = lane & 15, q = lane >> 4;
  const int ke0 = (q ^ (fr & 7)) << 3;         // swizzled k-chunk, ks=0
  const int ke1 = ((4 + q) ^ (fr & 7)) << 3;   // ks=1

  const int sr1 = (w << 4) + (lane >> 3);      // 0..127
  const int sr2 = sr1 + 8;
  const int kcp = lane & 7;
  const long off1 = (long)sr1 * lda + ((kcp ^ (sr1 & 7)) << 3);
  const long off2 = (long)sr2 * lda + ((kcp ^ (sr2 & 7)) << 3);
  const int lo1 = (w << 10) + (lane << 3);
  const int lo2 = lo1 + 512;
  const long h128 = 128L * lda;

  const u16* gA = A + bm * 256 * lda;
  const u16* gB = Bt + bn * 256 * lda;

  f32x4 acc00[4][2], acc01[4][2], acc10[4][2], acc11[4][2];
#pragma unroll
  for (int i = 0; i < 4; ++i)
#pragma unroll
    for (int j = 0; j < 2; ++j) {
      acc00[i][j] = (f32x4){0.f, 0.f, 0.f, 0.f};
      acc01[i][j] = (f32x4){0.f, 0.f, 0.f, 0.f};
      acc10[i][j] = (f32x4){0.f, 0.f, 0.f, 0.f};
      acc11[i][j] = (f32x4){0.f, 0.f, 0.f, 0.f};
    }

  const int NT = Klen >> 6;

  // ---- prologue: stage tiles 0 and 1 fully; first 4 halves = tile 0 ----
  STAGE(gA, 0L, 0L, 0, Abuf);     // A0 T0
  STAGE(gB, 0L, 0L, 0, Bbuf);     // B0 T0
  STAGE(gB, h128, 0L, 1, Bbuf);   // B1 T0
  STAGE(gA, h128, 0L, 1, Abuf);   // A1 T0
  STAGE(gA, 0L, 64L, 2, Abuf);    // A0 T1
  STAGE(gB, 0L, 64L, 2, Bbuf);    // B0 T1
  STAGE(gB, h128, 64L, 3, Bbuf);  // B1 T1
  STAGE(gA, h128, 64L, 3, Abuf);  // A1 T1
  asm volatile("s_waitcnt vmcnt(8)" ::: "memory");  // tile-0 halves landed
  __builtin_amdgcn_s_barrier();

  for (int T = 0; T < NT; ++T) {
    const int t2 = (T << 1) & 3;
    const int t2p1 = (t2 + 1) & 3;
    const long kT2 = (long)(T + 2) << 6;
    const bool g2 = (T + 2 < NT);
    bf16x8 a0[4][2], a1[4][2], b0[2][2], b1[2][2];

    // ---- phase 1: quadrant (A0,B0); no staging ----
    LDAF(a0, t2);
    LDBF(b0, t2);
    asm volatile("s_waitcnt lgkmcnt(8)" ::: "memory");
    __builtin_amdgcn_s_barrier();
    PH_FENCE();
    __builtin_amdgcn_s_setprio(1);
    MFMA16(acc00, a0, b0);
    __builtin_amdgcn_s_setprio(0);
    __builtin_amdgcn_s_barrier();

    // ---- phase 2: quadrant (A0,B1); stage A0(T+2) ----
    LDBF(b1, t2p1);
    if (g2) STAGE(gA, 0L, kT2, t2, Abuf);
    __builtin_amdgcn_s_barrier();
    PH_FENCE();
    __builtin_amdgcn_s_setprio(1);
    MFMA16(acc01, a0, b1);
    __builtin_amdgcn_s_setprio(0);
    __builtin_amdgcn_s_barrier();

    // ---- phase 3: quadrant (A1,B0); stage B0(T+2) ----
    LDAF(a1, t2p1);
    if (g2) STAGE(gB, 0L, kT2, t2, Bbuf);
    __builtin_amdgcn_s_barrier();
    PH_FENCE();
    __builtin_amdgcn_s_setprio(1);
    MFMA16(acc10, a1, b0);
    __builtin_amdgcn_s_setprio(0);
    __builtin_amdgcn_s_barrier();

    // ---- phase 4: quadrant (A1,B1); stage B1(T+2)+A1(T+2); single wait ----
    if (g2) {
      STAGE(gB, h128, kT2, t2p1, Bbuf);
      STAGE(gA, h128, kT2, t2p1, Abuf);
    }
    __builtin_amdgcn_s_barrier();
    PH_FENCE();
    __builtin_amdgcn_s_setprio(1);
    MFMA16(acc11, a1, b1);
    __builtin_amdgcn_s_setprio(0);
    if (g2)
      asm volatile("s_waitcnt vmcnt(8)" ::: "memory");
    else
      asm volatile("s_waitcnt vmcnt(0)" ::: "memory");
    __builtin_amdgcn_s_barrier();
  }

  // ---- epilogue: C write, col-guarded ----
  const int cr = (lane >> 4) << 2;
  const int cc = lane & 15;
  const long r0 = bm * 256 + wm * 64 + cr;
  const long c0 = bn * 256 + wn * 32 + cc;
#define CWRITE(ACC, QA, QB)                                                    \
  _Pragma("unroll") for (int i_ = 0; i_ < 4; ++i_)                             \
  _Pragma("unroll") for (int j_ = 0; j_ < 2; ++j_) {                           \
    long r_ = r0 + (QA)*128 + i_ * 16;                                         \
    long c_ = c0 + (QB)*128 + j_ * 16;                                         \
    if (c_ < N) {                                                              \
      float* cp_ = C + r_ * (long)N + c_;                                      \
      _Pragma("unroll") for (int t_ = 0; t_ < 4; ++t_)                         \
          cp_[(long)t_ * N] = ACC[i_][j_][t_];                                 \
    }                                                                          \
  }
  CWRITE(acc00, 0, 0)
  CWRITE(acc01, 0, 1)
  CWRITE(acc10, 1, 0)
  CWRITE(acc11, 1, 1)
#undef CWRITE
}

// ---------- split-K-4 partial add: out = p0+p1+p2+p3 (compact [2048][4096]) ----------
__global__ __launch_bounds__(256) void add4_kernel(const float* __restrict__ a,
                                                   float* __restrict__ o) {
  int i = blockIdx.x * 256 + threadIdx.x;
  f32x4 r = ((const f32x4*)a)[i];
  r += ((const f32x4*)(a + 4194304L))[i];
  r += ((const f32x4*)(a + 8388608L))[i];
  r += ((const f32x4*)(a + 12582912L))[i];
  ((f32x4*)o)[i] = r;
}

// ---------- strip split-K-4 add: proj[:,8192+..] = sum of 4 partials [2048][384] ----------
__global__ __launch_bounds__(256) void strip_add(const float* __restrict__ a,
                                                 float* __restrict__ proj) {
  int g = blockIdx.x * 256 + threadIdx.x;   // 0 .. 2048*96-1 (f32x4 groups)
  int r = g / 96, c4 = g - r * 96;
  f32x4 v = ((const f32x4*)a)[g];
  v += ((const f32x4*)(a + 786432L))[g];
  v += ((const f32x4*)(a + 1572864L))[g];
  v += ((const f32x4*)(a + 2359296L))[g];
  ((f32x4*)(proj + (long)r * LDP + 8192))[c4] = v;
}

// ---------- fused depthwise conv (K=4) + SiLU -> xbf AND xT (transposed) ----------
__global__ __launch_bounds__(256) void conv_silu_t(const float* __restrict__ proj,
                                                   const float* __restrict__ cw,
                                                   const float* __restrict__ cb,
                                                   u16* __restrict__ xbf,
                                                   u16* __restrict__ xT) {
  __shared__ float ld[35][33];
  __shared__ u16 tt[32][34];
  const int c0 = blockIdx.x * 32, t0 = blockIdx.y * 32;
  const int tx = threadIdx.x & 31, ty = threadIdx.x >> 5;
  for (int i = ty; i < 35; i += 8) {
    int t = t0 - 3 + i;
    ld[i][tx] = (t >= 0) ? proj[(long)t * LDP + INTER + c0 + tx] : 0.f;
  }
  const int c = c0 + tx;
  const float w0 = cw[c * 4 + 0], w1 = cw[c * 4 + 1], w2 = cw[c * 4 + 2],
              w3 = cw[c * 4 + 3], bias = cb[c];
  __syncthreads();
  for (int i = ty; i < 32; i += 8) {
    float a = bias + w0 * ld[i][tx] + w1 * ld[i + 1][tx] + w2 * ld[i + 2][tx] +
              w3 * ld[i + 3][tx];
    u16 v = f2bf(a / (1.f + __expf(-a)));
    xbf[(long)(t0 + i) * CONVD + c] = v;
    tt[i][tx] = v;
  }
  __syncthreads();
  if (c0 < 4224) {   // x + B + C regions get transposed
    for (int i = ty; i < 32; i += 8)
      xT[(long)(c0 + i) * 2048 + t0 + tx] = tt[tx][i];
  }
}

// ---------- dt softplus + per-chunk cumsum (Hillis-Steele), [h][t] layout ----------
__global__ __launch_bounds__(256) void dt_cumsum(const float* __restrict__ proj,
                                                 const float* __restrict__ dtb,
                                                 const float* __restrict__ A,
                                                 float* __restrict__ dt2,
                                                 float* __restrict__ cA2) {
  __shared__ float sc[256];
  int c = blockIdx.x, h = blockIdx.y, l = threadIdx.x;
  float v = proj[(long)(c * 256 + l) * LDP + 8448 + h] + dtb[h];
  float sp = (v > 20.f) ? v : log1pf(__expf(v));
  dt2[h * 2048 + c * 256 + l] = sp;
  sc[l] = sp * A[h];
  __syncthreads();
  for (int off = 1; off < 256; off <<= 1) {
    float t = (l >= off) ? sc[l - off] : 0.f;
    __syncthreads();
    sc[l] += t;
    __syncthreads();
  }
  cA2[h * 2048 + c * 256 + l] = sc[l];
}

// ---------- CB[c][l][s] = C[l,:].B[s,:] via MFMA, per-chunk strided GEMM ----------
__global__ __launch_bounds__(256, 2) void cb_gemm(const u16* __restrict__ xbf,
                                                  float* __restrict__ CB) {
  __shared__ __align__(16) u16 As[128 * 32];
  __shared__ __align__(16) u16 Bs[128 * 32];
  const int tid = threadIdx.x;
  const int lane = tid & 63;
  const int w = tid >> 6;
  const int wm = w >> 1, wn = w & 1;
  const int bm = blockIdx.y, bn = blockIdx.x, c = blockIdx.z;

  f32x4 acc[4][4];
#pragma unroll
  for (int i = 0; i < 4; ++i)
#pragma unroll
    for (int j = 0; j < 4; ++j) acc[i][j] = (f32x4){0.f, 0.f, 0.f, 0.f};

  const int sr = w * 32 + (lane >> 2);
  const int sc = ((lane & 3) ^ ((lane >> 2) & 3)) * 8;
  const u16* Ag = xbf + (long)(c * 256 + bm * 128) * CONVD + 4224;  // C region
  const u16* Bg = xbf + (long)(c * 256 + bn * 128) * CONVD + 4096;  // B region
  u16* lA0 = As + w * 1024 + lane * 8;
  u16* lA1 = As + w * 1024 + 512 + lane * 8;
  u16* lB0 = Bs + w * 1024 + lane * 8;
  u16* lB1 = Bs + w * 1024 + 512 + lane * 8;
  const int fr = lane & 15, q = lane >> 4;
  const int pc = ((q ^ (fr & 3)) << 3);

  for (int k0 = 0; k0 < 128; k0 += 32) {
    __syncthreads();
    const u16* a0 = Ag + (long)sr * CONVD + k0 + sc;
    const u16* b0 = Bg + (long)sr * CONVD + k0 + sc;
    gl2lds16(a0, lA0);
    gl2lds16(a0 + 16L * CONVD, lA1);
    gl2lds16(b0, lB0);
    gl2lds16(b0 + 16L * CONVD, lB1);
    __builtin_amdgcn_s_waitcnt(0);
    __syncthreads();
    bf16x8 af[4], bfv[4];
#pragma unroll
    for (int i = 0; i < 4; ++i)
      af[i] = *(const bf16x8*)(As + ((wm * 64 + i * 16 + fr) << 5) + pc);
#pragma unroll
    for (int j = 0; j < 4; ++j)
      bfv[j] = *(const bf16x8*)(Bs + ((wn * 64 + j * 16 + fr) << 5) + pc);
#pragma unroll
    for (int i = 0; i < 4; ++i)
#pragma unroll
      for (int j = 0; j < 4; ++j)
        acc[i][j] = __builtin_amdgcn_mfma_f32_16x16x32_bf16(af[i], bfv[j], acc[i][j], 0, 0, 0);
  }
  const int cr = (lane >> 4) * 4;
  const int cc = lane & 15;
  float* Cc = CB + (long)c * 65536;
#pragma unroll
  for (int i = 0; i < 4; ++i)
#pragma unroll
    for (int j = 0; j < 4; ++j) {
      int r = bm * 128 + wm * 64 + i * 16 + cr;
      int cidx = bn * 128 + wn * 64 + j * 16 + cc;
      float* cp = Cc + (long)r * 256 + cidx;
#pragma unroll
      for (int t = 0; t < 4; ++t) cp[t * 256] = acc[i][j][t];
    }
}

// ---------- states via MFMA: stT[n][p] = sum_l (B[l][n]*wl[l]) * x[l][p] ----------
#define LDM 72
__global__ __launch_bounds__(256) void states_kernel(const u16* __restrict__ xT,
                                                     const float* __restrict__ dt2,
                                                     const float* __restrict__ cA2,
                                                     float* __restrict__ stT) {
  __shared__ __align__(16) u16 Ms[128 * LDM];  // Bw [n][l_local]
  __shared__ __align__(16) u16 Xs[64 * LDM];   // x  [p][l_local]
  __shared__ float wl[256];
  const int c = blockIdx.x, h = blockIdx.y;
  const int tid = threadIdx.x;
  const int lane = tid & 63, w = tid >> 6;
  const int fr = lane & 15, q = lane >> 4;
  {
    float calast = cA2[h * 2048 + c * 256 + 255];
    float ca = cA2[h * 2048 + c * 256 + tid];
    wl[tid] = __expf(calast - ca) * dt2[h * 2048 + c * 256 + tid];
  }
  f32x4 acc[2][4];
#pragma unroll
  for (int i = 0; i < 2; ++i)
#pragma unroll
    for (int j = 0; j < 4; ++j) acc[i][j] = (f32x4){0.f, 0.f, 0.f, 0.f};

  const int lc8 = (tid & 7) * 8;
  const int rn = tid >> 3;   // 0..31
  __syncthreads();

  for (int kt = 0; kt < 4; ++kt) {
    __syncthreads();
#pragma unroll
    for (int r = 0; r < 4; ++r) {
      int n = rn + 32 * r;
      u16x8 raw = *(const u16x8*)(xT + (long)(4096 + n) * 2048 + c * 256 + kt * 64 + lc8);
      union { u16 u[8]; bf16x8 v; } pk;
#pragma unroll
      for (int u = 0; u < 8; ++u)
        pk.u[u] = f2bf(bf2f(raw[u]) * wl[kt * 64 + lc8 + u]);
      *(bf16x8*)(Ms + n * LDM + lc8) = pk.v;
    }
#pragma unroll
    for (int r = 0; r < 2; ++r) {
      int p = rn + 32 * r;
      *(bf16x8*)(Xs + p * LDM + lc8) =
          *(const bf16x8*)(xT + (long)(h * 64 + p) * 2048 + c * 256 + kt * 64 + lc8);
    }
    __syncthreads();
#pragma unroll
    for (int ks = 0; ks < 64; ks += 32) {
      bf16x8 af[2], xf[4];
#pragma unroll
      for (int i = 0; i < 2; ++i)
        af[i] = *(const bf16x8*)(Ms + (w * 32 + i * 16 + fr) * LDM + ks + q * 8);
#pragma unroll
      for (int j = 0; j < 4; ++j)
        xf[j] = *(const bf16x8*)(Xs + (j * 16 + fr) * LDM + ks + q * 8);
#pragma unroll
      for (int i = 0; i < 2; ++i)
#pragma unroll
        for (int j = 0; j < 4; ++j)
          acc[i][j] = __builtin_amdgcn_mfma_f32_16x16x32_bf16(af[i], xf[j], acc[i][j], 0, 0, 0);
    }
  }
  const int cr = (lane >> 4) * 4;
  const int cc = lane & 15;
  float* outp = stT + (long)(c * 64 + h) * 8192;
#pragma unroll
  for (int i = 0; i < 2; ++i)
#pragma unroll
    for (int j = 0; j < 4; ++j) {
      int n = w * 32 + i * 16 + cr;
      int p = j * 16 + cc;
#pragma unroll
      for (int t = 0; t < 4; ++t) outp[(n + t) * 64 + p] = acc[i][j][t];
    }
}

// ---------- 8-chunk inter-chunk scan ----------
__global__ __launch_bounds__(256) void scan_kernel(const float* __restrict__ stT,
                                                   const float* __restrict__ cA2,
                                                   float* __restrict__ prevT) {
  int id = blockIdx.x * 256 + threadIdx.x;   // h*8192 + n*64 + p
  int h = id >> 13;
  float acc = 0.f;
#pragma unroll
  for (int c = 0; c < NC; ++c) {
    prevT[(long)c * 524288 + id] = acc;
    float cd = __expf(cA2[h * 2048 + c * 256 + 255]);
    acc = acc * cd + stT[(long)c * 524288 + id];
  }
}

// ---------- intra+inter SSM output via bf16 MFMA ----------
__global__ __launch_bounds__(256) void ssm_y_kernel(const u16* __restrict__ xbf,
                                                    const u16* __restrict__ xT,
                                                    const float* __restrict__ dt2,
                                                    const float* __restrict__ cA2,
                                                    const float* __restrict__ CB,
                                                    const float* __restrict__ prevT,
                                                    const float* __restrict__ Dp,
                                                    u16* __restrict__ Y) {
  __shared__ __align__(16) u16 Ms[256 * LDM];
  __shared__ __align__(16) u16 Xt[64 * LDM];
  __shared__ float cas[256];
  __shared__ float dts[256];
  const int c = blockIdx.x, h = blockIdx.y;
  const int tid = threadIdx.x;
  const int lane = tid & 63;
  const int w = tid >> 6;
  const int fr = lane & 15, q = lane >> 4;

  cas[tid] = cA2[h * 2048 + c * 256 + tid];
  dts[tid] = dt2[h * 2048 + c * 256 + tid];

  f32x4 acc[4][4];
#pragma unroll
  for (int i = 0; i < 4; ++i)
#pragma unroll
    for (int j = 0; j < 4; ++j) acc[i][j] = (f32x4){0.f, 0.f, 0.f, 0.f};

  const int sg = (tid & 7) * 8;
  const int lb = tid >> 3;
  const int xp = tid & 63;
  const int xq = tid >> 6;

  __syncthreads();

  for (int kt = 0; kt < 6; ++kt) {
    __syncthreads();
    if (kt < 4) {
      const int s0 = kt * 64;
      f32x4 e0 = *(const f32x4*)&cas[s0 + sg];
      f32x4 e1 = *(const f32x4*)&cas[s0 + sg + 4];
      f32x4 d0 = *(const f32x4*)&dts[s0 + sg];
      f32x4 d1 = *(const f32x4*)&dts[s0 + sg + 4];
#pragma unroll
      for (int k = 0; k < 8; ++k) {
        const int l = lb + 32 * k;
        const float cal = cas[l];
        const float* cb = CB + (long)c * 65536 + (long)l * 256 + s0 + sg;
        f32x4 c0 = *(const f32x4*)cb;
        f32x4 c1 = *(const f32x4*)(cb + 4);
        union { u16 u[8]; bf16x8 v; } pk;
#pragma unroll
        for (int u = 0; u < 8; ++u) {
          int s = s0 + sg + u;
          float cv = (u < 4) ? c0[u] : c1[u - 4];
          float cs = (u < 4) ? e0[u] : e1[u - 4];
          float dv = (u < 4) ? d0[u] : d1[u - 4];
          float m = (s <= l) ? cv * __expf(cal - cs) * dv : 0.f;
          pk.u[u] = f2bf(m);
        }
        *(bf16x8*)(Ms + l * LDM + sg) = pk.v;
      }
#pragma unroll
      for (int r = 0; r < 2; ++r) {
        int p = (tid >> 3) + 32 * r;
        *(bf16x8*)(Xt + p * LDM + sg) =
            *(const bf16x8*)(xT + (long)(h * 64 + p) * 2048 + c * 256 + s0 + sg);
      }
    } else {
      const int n0 = (kt - 4) * 64;
#pragma unroll
      for (int k = 0; k < 8; ++k) {
        const int l = lb + 32 * k;
        const float ea = __expf(cas[l]);
        u16x8 raw = *(const u16x8*)(xbf + (long)(c * 256 + l) * CONVD + 4224 + n0 + sg);
        union { u16 u[8]; bf16x8 v; } pk;
#pragma unroll
        for (int u = 0; u < 8; ++u) pk.u[u] = f2bf(ea * bf2f(raw[u]));
        *(bf16x8*)(Ms + l * LDM + sg) = pk.v;
      }
      const float* pT = prevT + (long)(c * 64 + h) * 8192;
#pragma unroll
      for (int half = 0; half < 2; ++half) {
        const int nb2 = xq * 16 + half * 8;
        union { u16 u[8]; bf16x8 v; } pk;
#pragma unroll
        for (int u = 0; u < 8; ++u) pk.u[u] = f2bf(pT[(n0 + nb2 + u) * 64 + xp]);
        *(bf16x8*)(Xt + xp * LDM + nb2) = pk.v;
      }
    }
    __syncthreads();
#pragma unroll
    for (int ks = 0; ks < 64; ks += 32) {
      bf16x8 af[4], bfv[4];
#pragma unroll
      for (int i = 0; i < 4; ++i)
        af[i] = *(const bf16x8*)(Ms + (w * 64 + i * 16 + fr) * LDM + ks + q * 8);
#pragma unroll
      for (int j = 0; j < 4; ++j)
        bfv[j] = *(const bf16x8*)(Xt + (j * 16 + fr) * LDM + ks + q * 8);
#pragma unroll
      for (int i = 0; i < 4; ++i)
#pragma unroll
        for (int j = 0; j < 4; ++j)
          acc[i][j] = __builtin_amdgcn_mfma_f32_16x16x32_bf16(af[i], bfv[j], acc[i][j], 0, 0, 0);
    }
  }

  const int cr = (lane >> 4) * 4;
  const int cc = lane & 15;
  const float dh = Dp[h];
#pragma unroll
  for (int i = 0; i < 4; ++i)
#pragma unroll
    for (int j = 0; j < 4; ++j) {
      const int p = j * 16 + cc;
#pragma unroll
      for (int t = 0; t < 4; ++t) {
        const int row = w * 64 + i * 16 + cr + t;
        const float xv = bf2f(xbf[(long)(c * 256 + row) * CONVD + h * 64 + p]);
        Y[(long)(c * 256 + row) * 4096 + h * 64 + p] = f2bf(acc[i][j][t] + dh * xv);
      }
    }
}

// ---------- gated RMSNorm (Y in bf16) -> bf16 z ----------
__global__ __launch_bounds__(256) void rmsnorm_kernel(const u16* __restrict__ Y,
                                                      const float* __restrict__ proj,
                                                      const float* __restrict__ nw,
                                                      u16* __restrict__ zbf) {
  __shared__ float red[256];
  int t = blockIdx.x, tid = threadIdx.x;
  const u16* y = Y + (long)t * 4096;
  const float* g = proj + (long)t * LDP;
  float zv[16];
  float s = 0.f;
#pragma unroll
  for (int k = 0; k < 16; ++k) {
    int i = tid + k * 256;
    float gv = g[i];
    float z = bf2f(y[i]) * (gv / (1.f + __expf(-gv)));
    zv[k] = z;
    s += z * z;
  }
  red[tid] = s;
  __syncthreads();
  if (tid < 128) red[tid] += red[tid + 128];
  __syncthreads();
  if (tid < 64) {
    float v = red[tid] + red[tid + 64];
    v += __shfl_down(v, 32);
    v += __shfl_down(v, 16);
    v += __shfl_down(v, 8);
    v += __shfl_down(v, 4);
    v += __shfl_down(v, 2);
    v += __shfl_down(v, 1);
    if (tid == 0) red[0] = v;
  }
  __syncthreads();
  float scale = rsqrtf(red[0] * (1.f / 4096.f) + 1e-5f);
#pragma unroll
  for (int k = 0; k < 16; ++k) {
    int i = tid + k * 256;
    zbf[(long)t * 4096 + i] = f2bf(zv[k] * scale * nw[i]);
  }
}

// ---------- launch ----------
extern "C" void kernel_launch(void* const* d_in, const int* in_sizes, int n_in,
                              void* d_out, int out_size, void* d_ws, size_t ws_size,
                              hipStream_t stream) {
  const float* hidden = (const float*)d_in[0];
  const float* Win    = (const float*)d_in[1];
  const float* convw  = (const float*)d_in[2];
  const float* convb  = (const float*)d_in[3];
  const float* dtb    = (const float*)d_in[4];
  const float* Ap     = (const float*)d_in[5];
  const float* Dp     = (const float*)d_in[6];
  const float* nw     = (const float*)d_in[7];
  const float* Wout   = (const float*)d_in[8];
  float* out = (float*)d_out;
  char* ws = (char*)d_ws;

  // workspace layout (bytes) — identical footprint to the verified layout.
  u16*   hb    = (u16*)(ws + 0);            //  8,388,608
  u16*   WinT  = (u16*)(ws + 8388608L);     // 35,127,296  [8576][2048] bf16
  float* proj  = (float*)(ws + 43515904L);  // 70,254,592  [2048][8576] f32
  u16*   WoutT = (u16*)(ws + 113770496L);   // 16,777,216  [2048][4096] bf16
  u16*   xbf   = (u16*)(ws + 130547712L);   // 17,825,792  [2048][4352] bf16
  u16*   xT    = (u16*)(ws + 148373504L);   // 17,301,504  [4224][2048] bf16
  float* dt2   = (float*)(ws + 165675008L); //    524,288  [64][2048]
  float* cA2   = (float*)(ws + 166199296L); //    524,288  [64][2048]
  float* CBv   = (float*)(ws + 166723584L); //  2,097,152  [8][256][256]
  float* stT   = (float*)(ws + 168820736L); // 16,777,216  [8][64][128][64]
  float* prevT = (float*)(ws + 185597952L); // 16,777,216
  u16*   zbf   = (u16*)(ws + 202375168L);   // 16,777,216  [2048][4096] bf16
  u16*   Y     = (u16*)(ws + 0);            // 16,777,216  bf16 (overlay hb+WinT, dead)
  float* Cp    = (float*)(ws + 43515904L);  // 67,108,864  GEMM2 partials x4 (overlay proj)
  float* Cs    = (float*)(ws + 168820736L); // 12,582,912  strip partials x4 (overlay stT, dead here)

  cvt_bf16<<<4096, 256, 0, stream>>>(hidden, hb, 1048576);
  transpose_bf16<<<dim3(268, 64), dim3(32, 8), 0, stream>>>(Win, WinT, 2048, 8512);
  transpose_bf16<<<dim3(64, 128), dim3(32, 8), 0, stream>>>(Wout, WoutT, 4096, 2048);
  // in-proj main: gate+x cols [0,8192) = 8x32 tiles of 256^2, 256 blocks
  gemm256<<<dim3(32, 8, 1), 512, 0, stream>>>(hb, WinT, proj, 8576, 2048, 2048, 0L);
  // in-proj strip: B/C/dt cols [8192,8576), split-K4 (192 blocks of K=512) + add
  gemm_bt<<<dim3(3, 16, 4), 256, 0, stream>>>(hb, WinT + 8192L * 2048, Cs,
                                              384, 2048, 512, 786432L);
  strip_add<<<768, 256, 0, stream>>>(Cs, proj);
  conv_silu_t<<<dim3(136, 64), 256, 0, stream>>>(proj, convw, convb, xbf, xT);
  dt_cumsum<<<dim3(8, 64), 256, 0, stream>>>(proj, dtb, Ap, dt2, cA2);
  cb_gemm<<<dim3(2, 2, 8), 256, 0, stream>>>(xbf, CBv);
  states_kernel<<<dim3(8, 64), 256, 0, stream>>>(xT, dt2, cA2, stT);
  scan_kernel<<<2048, 256, 0, stream>>>(stT, cA2, prevT);
  ssm_y_kernel<<<dim3(8, 64), 256, 0, stream>>>(xbf, xT, dt2, cA2, CBv, prevT, Dp, Y);
  rmsnorm_kernel<<<2048, 256, 0, stream>>>(Y, proj, nw, zbf);
  // out-proj: 8x8 tiles x split-K4 = 256 blocks, perfect packing
  gemm256<<<dim3(8, 8, 4), 512, 0, stream>>>(zbf, WoutT, Cp, 2048, 4096, 1024, 4194304L);
  add4_kernel<<<4096, 256, 0, stream>>>(Cp, out);
}

// Round 7
// 389.204 us; speedup vs baseline: 1.1446x; 1.0474x over previous
//
#include <hip/hip_runtime.h>

// ---------- types ----------
typedef __bf16 bf16_t;
typedef bf16_t bf16x8 __attribute__((ext_vector_type(8)));
typedef float f32x4 __attribute__((ext_vector_type(4)));
typedef unsigned short u16;
typedef u16 u16x8 __attribute__((ext_vector_type(8)));
typedef u16 u16x4 __attribute__((ext_vector_type(4)));

// ---------- model dims ----------
#define SEQ   2048
#define HID   2048
#define INTER 4096
#define NH    64
#define HD    64
#define CONVD 4352
#define DIN   8512
#define CHNK  256
#define NC    8

__device__ __forceinline__ u16 f2bf(float f) {
  union { float f; unsigned u; } a; a.f = f;
  return (u16)((a.u + 0x7fffu + ((a.u >> 16) & 1u)) >> 16);
}
__device__ __forceinline__ float bf2f(u16 u) {
  union { unsigned u; float f; } a; a.u = ((unsigned)u) << 16;
  return a.f;
}

__device__ __forceinline__ void gl2lds16(const void* g, void* l) {
  auto gp = reinterpret_cast<__attribute__((address_space(1))) void*>(
      (unsigned long long)g);
  auto lp = reinterpret_cast<__attribute__((address_space(3))) void*>(
      (unsigned)(unsigned long long)l);
  __builtin_amdgcn_global_load_lds(gp, lp, 16, 0, 0);
}

// forced-register LDS vector read
__device__ __forceinline__ bf16x8 ds128(unsigned addr) {
  bf16x8 r;
  asm volatile("ds_read_b128 %0, %1" : "=v"(r) : "v"(addr));
  return r;
}

// ---------- fp32 -> bf16 flat convert (vectorized, n4 = n/4) ----------
__global__ __launch_bounds__(256) void cvt_bf16(const float* __restrict__ s,
                                                u16* __restrict__ d, int n4) {
  int i = blockIdx.x * 256 + threadIdx.x;
  if (i < n4) {
    f32x4 v = ((const f32x4*)s)[i];
    u16x4 r;
#pragma unroll
    for (int k = 0; k < 4; ++k) r[k] = f2bf(v[k]);
    ((u16x4*)d)[i] = r;
  }
}

// ---------- transpose + convert: src[R][Cc] f32 -> dst[n][R] bf16, 64x64 tiles ----------
// vectorized: f32x4 loads, u16x8 stores (128 B per 8-lane group); zero-pad n>=Cc.
__global__ __launch_bounds__(256) void transpose_bf16(const float* __restrict__ src,
                                                      u16* __restrict__ dst,
                                                      int R, int Cc) {
  __shared__ u16 t[64][72];
  const int n0 = blockIdx.x * 64, k0 = blockIdx.y * 64;
  const int tx = threadIdx.x & 15;   // n/4 group
  const int ty = threadIdx.x >> 4;   // k row base
  if (n0 + 63 < Cc) {
#pragma unroll
    for (int j = 0; j < 4; ++j) {
      int k = ty + j * 16;
      f32x4 v = *(const f32x4*)(src + (long)(k0 + k) * Cc + n0 + tx * 4);
#pragma unroll
      for (int e = 0; e < 4; ++e) t[tx * 4 + e][k] = f2bf(v[e]);
    }
  } else {
#pragma unroll
    for (int j = 0; j < 4; ++j) {
      int k = ty + j * 16;
#pragma unroll
      for (int e = 0; e < 4; ++e) {
        int n = n0 + tx * 4 + e;
        t[tx * 4 + e][k] = (n < Cc) ? f2bf(src[(long)(k0 + k) * Cc + n]) : (u16)0;
      }
    }
  }
  __syncthreads();
  const int cg = threadIdx.x & 7;
  const int r0 = threadIdx.x >> 3;   // 0..31
#pragma unroll
  for (int j = 0; j < 2; ++j) {
    int row = r0 + j * 32;
    u16x8 o;
#pragma unroll
    for (int e = 0; e < 8; ++e) o[e] = t[row][cg * 8 + e];
    *(u16x8*)(dst + (long)(n0 + row) * R + k0 + cg * 8) = o;
  }
}

// ---------- bf16 MFMA GEMM: 128x128 tile, BK=64 (384-col strip, f32 out) ----------
__global__ __launch_bounds__(256, 2) void gemm_bt(const u16* __restrict__ A,
                                                  const u16* __restrict__ Bt,
                                                  float* __restrict__ C,
                                                  int N, int lda, int Klen,
                                                  long zstride) {
  __shared__ __align__(16) u16 As[128 * 64];
  __shared__ __align__(16) u16 Bs[128 * 64];
  const int kz = blockIdx.z;
  A  += (long)kz * Klen;
  Bt += (long)kz * Klen;
  C  += (long)kz * zstride;
  const int nb = gridDim.x * gridDim.y;
  const int id = blockIdx.x + gridDim.x * blockIdx.y;
  const int s = (id & 7) * (nb >> 3) + (id >> 3);
  const long bm = s & 15;
  const long bn = s >> 4;

  const int tid = threadIdx.x;
  const int lane = tid & 63;
  const int w = tid >> 6;
  const int wm = w >> 1, wn = w & 1;

  f32x4 acc[4][4];
#pragma unroll
  for (int i = 0; i < 4; ++i)
#pragma unroll
    for (int j = 0; j < 4; ++j) acc[i][j] = (f32x4){0.f, 0.f, 0.f, 0.f};

  const int srr = lane >> 3;
  const int sc8 = ((lane & 7) ^ srr) * 8;
  const u16* Agw = A + (bm * 128 + w * 8 + srr) * (long)lda + sc8;
  const u16* Bgw = Bt + (bn * 128 + w * 8 + srr) * (long)lda + sc8;
  u16* ldA = As + w * 512 + lane * 8;
  u16* ldB = Bs + w * 512 + lane * 8;
  const int fr = lane & 15, q = lane >> 4;
  const int fx = (fr & 7) << 3;

  for (int k0 = 0; k0 < Klen; k0 += 64) {
    __syncthreads();
#pragma unroll
    for (int t = 0; t < 4; ++t) {
      gl2lds16(Agw + k0 + (long)t * 32 * lda, ldA + t * 2048);
      gl2lds16(Bgw + k0 + (long)t * 32 * lda, ldB + t * 2048);
    }
    __builtin_amdgcn_s_waitcnt(0);
    __syncthreads();
#pragma unroll
    for (int ks = 0; ks < 2; ++ks) {
      bf16x8 af[4], bfv[4];
#pragma unroll
      for (int i = 0; i < 4; ++i)
        af[i] = *(const bf16x8*)(As + ((wm * 64 + i * 16 + fr) << 6) +
                                 ((((ks << 2) + q) << 3) ^ fx));
#pragma unroll
      for (int j = 0; j < 4; ++j)
        bfv[j] = *(const bf16x8*)(Bs + ((wn * 64 + j * 16 + fr) << 6) +
                                  ((((ks << 2) + q) << 3) ^ fx));
#pragma unroll
      for (int i = 0; i < 4; ++i)
#pragma unroll
        for (int j = 0; j < 4; ++j)
          acc[i][j] = __builtin_amdgcn_mfma_f32_16x16x32_bf16(af[i], bfv[j], acc[i][j], 0, 0, 0);
    }
  }
  const int cr = (lane >> 4) * 4;
  const int cc = lane & 15;
#pragma unroll
  for (int i = 0; i < 4; ++i)
#pragma unroll
    for (int j = 0; j < 4; ++j) {
      long r = bm * 128 + wm * 64 + i * 16 + cr;
      long cidx = bn * 128 + wn * 64 + j * 16 + cc;
      float* cp = C + r * (long)N + cidx;
#pragma unroll
      for (int t = 0; t < 4; ++t) cp[(long)t * N] = acc[i][j][t];
    }
}

// ============================================================================
// 256x256-tile 8-phase bf16 MFMA GEMM, BK=64, 512 threads (verified schedule,
// round-6).  BFOUT=1 -> bf16 output (f2bf in epilogue), BFOUT=0 -> f32.
// ============================================================================
#define MFMA16(ACC, AF, BF)                                                    \
  _Pragma("unroll") for (int i_ = 0; i_ < 4; ++i_)                             \
  _Pragma("unroll") for (int j_ = 0; j_ < 2; ++j_) {                           \
    ACC[i_][j_] = __builtin_amdgcn_mfma_f32_16x16x32_bf16(                     \
        AF[i_][0], BF[j_][0], ACC[i_][j_], 0, 0, 0);                           \
    ACC[i_][j_] = __builtin_amdgcn_mfma_f32_16x16x32_bf16(                     \
        AF[i_][1], BF[j_][1], ACC[i_][j_], 0, 0, 0);                           \
  }

#define LDAF(DST, SLOT)                                                        \
  {                                                                            \
    unsigned ab_ = (unsigned)(unsigned long long)(&Abuf[SLOT][0]);             \
    _Pragma("unroll") for (int i_ = 0; i_ < 4; ++i_) {                         \
      unsigned ro_ = ab_ + (((wm * 64 + i_ * 16 + fr) << 6) << 1);             \
      DST[i_][0] = ds128(ro_ + (ke0 << 1));                                    \
      DST[i_][1] = ds128(ro_ + (ke1 << 1));                                    \
    }                                                                          \
  }

#define LDBF(DST, SLOT)                                                        \
  {                                                                            \
    unsigned bb_ = (unsigned)(unsigned long long)(&Bbuf[SLOT][0]);             \
    _Pragma("unroll") for (int j_ = 0; j_ < 2; ++j_) {                         \
      unsigned ro_ = bb_ + (((wn * 32 + j_ * 16 + fr) << 6) << 1);             \
      DST[j_][0] = ds128(ro_ + (ke0 << 1));                                    \
      DST[j_][1] = ds128(ro_ + (ke1 << 1));                                    \
    }                                                                          \
  }

#define STAGE(G, HO, KO, SLOT, BUF)                                            \
  {                                                                            \
    const u16* g_ = (G) + (HO) + (KO);                                         \
    gl2lds16(g_ + off1, BUF[SLOT] + lo1);                                      \
    gl2lds16(g_ + off2, BUF[SLOT] + lo2);                                      \
  }

#define PH_FENCE()                                                             \
  asm volatile("s_waitcnt lgkmcnt(0)" ::: "memory");                           \
  __builtin_amdgcn_sched_barrier(0);

template <int BFOUT>
__global__ __launch_bounds__(512, 2) void gemm256(const u16* __restrict__ A,
                                                  const u16* __restrict__ Bt,
                                                  void* __restrict__ Cv,
                                                  int N, int lda, int Klen,
                                                  long zstride) {
  __shared__ __align__(16) u16 Abuf[4][128 * 64];
  __shared__ __align__(16) u16 Bbuf[4][128 * 64];

  const int kz = blockIdx.z;
  A  += (long)kz * Klen;
  Bt += (long)kz * Klen;
  const long czoff = (long)kz * zstride;

  // XCD-contiguous remap (nb % 8 == 0)
  const int nb = gridDim.x * gridDim.y;
  const int id = blockIdx.x + gridDim.x * blockIdx.y;
  const int s = (id & 7) * (nb >> 3) + (id >> 3);
  const long bm = s & 7;
  const long bn = s >> 3;

  const int tid = threadIdx.x;
  const int lane = tid & 63;
  const int w = tid >> 6;        // wave 0..7
  const int wm = w >> 2;         // 0..1
  const int wn = w & 3;          // 0..3
  const int fr = lane & 15, q = lane >> 4;
  const int ke0 = (q ^ (fr & 7)) << 3;
  const int ke1 = ((4 + q) ^ (fr & 7)) << 3;

  const int sr1 = (w << 4) + (lane >> 3);
  const int sr2 = sr1 + 8;
  const int kcp = lane & 7;
  const long off1 = (long)sr1 * lda + ((kcp ^ (sr1 & 7)) << 3);
  const long off2 = (long)sr2 * lda + ((kcp ^ (sr2 & 7)) << 3);
  const int lo1 = (w << 10) + (lane << 3);
  const int lo2 = lo1 + 512;
  const long h128 = 128L * lda;

  const u16* gA = A + bm * 256 * lda;
  const u16* gB = Bt + bn * 256 * lda;

  f32x4 acc00[4][2], acc01[4][2], acc10[4][2], acc11[4][2];
#pragma unroll
  for (int i = 0; i < 4; ++i)
#pragma unroll
    for (int j = 0; j < 2; ++j) {
      acc00[i][j] = (f32x4){0.f, 0.f, 0.f, 0.f};
      acc01[i][j] = (f32x4){0.f, 0.f, 0.f, 0.f};
      acc10[i][j] = (f32x4){0.f, 0.f, 0.f, 0.f};
      acc11[i][j] = (f32x4){0.f, 0.f, 0.f, 0.f};
    }

  const int NT = Klen >> 6;

  // ---- prologue: stage tiles 0 and 1 fully ----
  STAGE(gA, 0L, 0L, 0, Abuf);
  STAGE(gB, 0L, 0L, 0, Bbuf);
  STAGE(gB, h128, 0L, 1, Bbuf);
  STAGE(gA, h128, 0L, 1, Abuf);
  STAGE(gA, 0L, 64L, 2, Abuf);
  STAGE(gB, 0L, 64L, 2, Bbuf);
  STAGE(gB, h128, 64L, 3, Bbuf);
  STAGE(gA, h128, 64L, 3, Abuf);
  asm volatile("s_waitcnt vmcnt(8)" ::: "memory");
  __builtin_amdgcn_s_barrier();

  for (int T = 0; T < NT; ++T) {
    const int t2 = (T << 1) & 3;
    const int t2p1 = (t2 + 1) & 3;
    const long kT2 = (long)(T + 2) << 6;
    const bool g2 = (T + 2 < NT);
    bf16x8 a0[4][2], a1[4][2], b0[2][2], b1[2][2];

    // ---- phase 1: quadrant (A0,B0) ----
    LDAF(a0, t2);
    LDBF(b0, t2);
    asm volatile("s_waitcnt lgkmcnt(8)" ::: "memory");
    __builtin_amdgcn_s_barrier();
    PH_FENCE();
    __builtin_amdgcn_s_setprio(1);
    MFMA16(acc00, a0, b0);
    __builtin_amdgcn_s_setprio(0);
    __builtin_amdgcn_s_barrier();

    // ---- phase 2: quadrant (A0,B1); stage A0(T+2) ----
    LDBF(b1, t2p1);
    if (g2) STAGE(gA, 0L, kT2, t2, Abuf);
    __builtin_amdgcn_s_barrier();
    PH_FENCE();
    __builtin_amdgcn_s_setprio(1);
    MFMA16(acc01, a0, b1);
    __builtin_amdgcn_s_setprio(0);
    __builtin_amdgcn_s_barrier();

    // ---- phase 3: quadrant (A1,B0); stage B0(T+2) ----
    LDAF(a1, t2p1);
    if (g2) STAGE(gB, 0L, kT2, t2, Bbuf);
    __builtin_amdgcn_s_barrier();
    PH_FENCE();
    __builtin_amdgcn_s_setprio(1);
    MFMA16(acc10, a1, b0);
    __builtin_amdgcn_s_setprio(0);
    __builtin_amdgcn_s_barrier();

    // ---- phase 4: quadrant (A1,B1); stage B1+A1(T+2); single wait ----
    if (g2) {
      STAGE(gB, h128, kT2, t2p1, Bbuf);
      STAGE(gA, h128, kT2, t2p1, Abuf);
    }
    __builtin_amdgcn_s_barrier();
    PH_FENCE();
    __builtin_amdgcn_s_setprio(1);
    MFMA16(acc11, a1, b1);
    __builtin_amdgcn_s_setprio(0);
    if (g2)
      asm volatile("s_waitcnt vmcnt(8)" ::: "memory");
    else
      asm volatile("s_waitcnt vmcnt(0)" ::: "memory");
    __builtin_amdgcn_s_barrier();
  }

  // ---- epilogue: C write, col-guarded; bf16 or f32 per BFOUT ----
  const int cr = (lane >> 4) << 2;
  const int cc = lane & 15;
  const long r0 = bm * 256 + wm * 64 + cr;
  const long c0 = bn * 256 + wn * 32 + cc;
#define CWRITE(ACC, QA, QB)                                                    \
  _Pragma("unroll") for (int i_ = 0; i_ < 4; ++i_)                             \
  _Pragma("unroll") for (int j_ = 0; j_ < 2; ++j_) {                           \
    long r_ = r0 + (QA)*128 + i_ * 16;                                         \
    long c_ = c0 + (QB)*128 + j_ * 16;                                         \
    if (c_ < N) {                                                              \
      long base_ = czoff + r_ * (long)N + c_;                                  \
      _Pragma("unroll") for (int t_ = 0; t_ < 4; ++t_) {                       \
        if (BFOUT)                                                             \
          ((u16*)Cv)[base_ + (long)t_ * N] = f2bf(ACC[i_][j_][t_]);            \
        else                                                                   \
          ((float*)Cv)[base_ + (long)t_ * N] = ACC[i_][j_][t_];                \
      }                                                                        \
    }                                                                          \
  }
  CWRITE(acc00, 0, 0)
  CWRITE(acc01, 0, 1)
  CWRITE(acc10, 1, 0)
  CWRITE(acc11, 1, 1)
#undef CWRITE
}

// ---------- split-K-4 partial add: out = p0+p1+p2+p3 (compact [2048][4096]) ----------
__global__ __launch_bounds__(256) void add4_kernel(const float* __restrict__ a,
                                                   float* __restrict__ o) {
  int i = blockIdx.x * 256 + threadIdx.x;
  f32x4 r = ((const f32x4*)a)[i];
  r += ((const f32x4*)(a + 4194304L))[i];
  r += ((const f32x4*)(a + 8388608L))[i];
  r += ((const f32x4*)(a + 12582912L))[i];
  ((f32x4*)o)[i] = r;
}

// ---------- strip split-K-4 add: ps[2048][384] = sum of 4 partials ----------
__global__ __launch_bounds__(256) void strip_add(const float* __restrict__ a,
                                                 float* __restrict__ ps) {
  int g = blockIdx.x * 256 + threadIdx.x;   // 0 .. 2048*96-1 (f32x4 groups)
  f32x4 v = ((const f32x4*)a)[g];
  v += ((const f32x4*)(a + 786432L))[g];
  v += ((const f32x4*)(a + 1572864L))[g];
  v += ((const f32x4*)(a + 2359296L))[g];
  ((f32x4*)ps)[g] = v;
}

// ---------- fused depthwise conv (K=4) + SiLU -> xbf AND xT (transposed) ----------
// x region (cols<4096) read from bf16 pb; B/C region from f32 ps.
__global__ __launch_bounds__(256) void conv_silu_t(const u16* __restrict__ pb,
                                                   const float* __restrict__ ps,
                                                   const float* __restrict__ cw,
                                                   const float* __restrict__ cb,
                                                   u16* __restrict__ xbf,
                                                   u16* __restrict__ xT) {
  __shared__ float ld[35][33];
  __shared__ u16 tt[32][34];
  const int c0 = blockIdx.x * 32, t0 = blockIdx.y * 32;
  const int tx = threadIdx.x & 31, ty = threadIdx.x >> 5;
  const bool mainreg = (c0 < 4096);
  for (int i = ty; i < 35; i += 8) {
    int t = t0 - 3 + i;
    float v = 0.f;
    if (t >= 0) {
      if (mainreg) v = bf2f(pb[(long)t * 8192 + 4096 + c0 + tx]);
      else         v = ps[(long)t * 384 + (c0 - 4096) + tx];
    }
    ld[i][tx] = v;
  }
  const int c = c0 + tx;
  const float w0 = cw[c * 4 + 0], w1 = cw[c * 4 + 1], w2 = cw[c * 4 + 2],
              w3 = cw[c * 4 + 3], bias = cb[c];
  __syncthreads();
  for (int i = ty; i < 32; i += 8) {
    float a = bias + w0 * ld[i][tx] + w1 * ld[i + 1][tx] + w2 * ld[i + 2][tx] +
              w3 * ld[i + 3][tx];
    u16 v = f2bf(a / (1.f + __expf(-a)));
    xbf[(long)(t0 + i) * CONVD + c] = v;
    tt[i][tx] = v;
  }
  __syncthreads();
  if (c0 < 4224) {   // x + B + C regions get transposed
    for (int i = ty; i < 32; i += 8)
      xT[(long)(c0 + i) * 2048 + t0 + tx] = tt[tx][i];
  }
}

// ---------- dt softplus + per-chunk cumsum (Hillis-Steele), [h][t] layout ----------
__global__ __launch_bounds__(256) void dt_cumsum(const float* __restrict__ ps,
                                                 const float* __restrict__ dtb,
                                                 const float* __restrict__ A,
                                                 float* __restrict__ dt2,
                                                 float* __restrict__ cA2) {
  __shared__ float sc[256];
  int c = blockIdx.x, h = blockIdx.y, l = threadIdx.x;
  float v = ps[(long)(c * 256 + l) * 384 + 256 + h] + dtb[h];
  float sp = (v > 20.f) ? v : log1pf(__expf(v));
  dt2[h * 2048 + c * 256 + l] = sp;
  sc[l] = sp * A[h];
  __syncthreads();
  for (int off = 1; off < 256; off <<= 1) {
    float t = (l >= off) ? sc[l - off] : 0.f;
    __syncthreads();
    sc[l] += t;
    __syncthreads();
  }
  cA2[h * 2048 + c * 256 + l] = sc[l];
}

// ---------- CB[c][l][s] = C[l,:].B[s,:] via MFMA, per-chunk strided GEMM ----------
__global__ __launch_bounds__(256, 2) void cb_gemm(const u16* __restrict__ xbf,
                                                  float* __restrict__ CB) {
  __shared__ __align__(16) u16 As[128 * 32];
  __shared__ __align__(16) u16 Bs[128 * 32];
  const int tid = threadIdx.x;
  const int lane = tid & 63;
  const int w = tid >> 6;
  const int wm = w >> 1, wn = w & 1;
  const int bm = blockIdx.y, bn = blockIdx.x, c = blockIdx.z;

  f32x4 acc[4][4];
#pragma unroll
  for (int i = 0; i < 4; ++i)
#pragma unroll
    for (int j = 0; j < 4; ++j) acc[i][j] = (f32x4){0.f, 0.f, 0.f, 0.f};

  const int sr = w * 32 + (lane >> 2);
  const int sc = ((lane & 3) ^ ((lane >> 2) & 3)) * 8;
  const u16* Ag = xbf + (long)(c * 256 + bm * 128) * CONVD + 4224;  // C region
  const u16* Bg = xbf + (long)(c * 256 + bn * 128) * CONVD + 4096;  // B region
  u16* lA0 = As + w * 1024 + lane * 8;
  u16* lA1 = As + w * 1024 + 512 + lane * 8;
  u16* lB0 = Bs + w * 1024 + lane * 8;
  u16* lB1 = Bs + w * 1024 + 512 + lane * 8;
  const int fr = lane & 15, q = lane >> 4;
  const int pc = ((q ^ (fr & 3)) << 3);

  for (int k0 = 0; k0 < 128; k0 += 32) {
    __syncthreads();
    const u16* a0 = Ag + (long)sr * CONVD + k0 + sc;
    const u16* b0 = Bg + (long)sr * CONVD + k0 + sc;
    gl2lds16(a0, lA0);
    gl2lds16(a0 + 16L * CONVD, lA1);
    gl2lds16(b0, lB0);
    gl2lds16(b0 + 16L * CONVD, lB1);
    __builtin_amdgcn_s_waitcnt(0);
    __syncthreads();
    bf16x8 af[4], bfv[4];
#pragma unroll
    for (int i = 0; i < 4; ++i)
      af[i] = *(const bf16x8*)(As + ((wm * 64 + i * 16 + fr) << 5) + pc);
#pragma unroll
    for (int j = 0; j < 4; ++j)
      bfv[j] = *(const bf16x8*)(Bs + ((wn * 64 + j * 16 + fr) << 5) + pc);
#pragma unroll
    for (int i = 0; i < 4; ++i)
#pragma unroll
      for (int j = 0; j < 4; ++j)
        acc[i][j] = __builtin_amdgcn_mfma_f32_16x16x32_bf16(af[i], bfv[j], acc[i][j], 0, 0, 0);
  }
  const int cr = (lane >> 4) * 4;
  const int cc = lane & 15;
  float* Cc = CB + (long)c * 65536;
#pragma unroll
  for (int i = 0; i < 4; ++i)
#pragma unroll
    for (int j = 0; j < 4; ++j) {
      int r = bm * 128 + wm * 64 + i * 16 + cr;
      int cidx = bn * 128 + wn * 64 + j * 16 + cc;
      float* cp = Cc + (long)r * 256 + cidx;
#pragma unroll
      for (int t = 0; t < 4; ++t) cp[t * 256] = acc[i][j][t];
    }
}

// ---------- states via MFMA: stT[n][p] = sum_l (B[l][n]*wl[l]) * x[l][p] ----------
#define LDM 72
__global__ __launch_bounds__(256) void states_kernel(const u16* __restrict__ xT,
                                                     const float* __restrict__ dt2,
                                                     const float* __restrict__ cA2,
                                                     float* __restrict__ stT) {
  __shared__ __align__(16) u16 Ms[128 * LDM];  // Bw [n][l_local]
  __shared__ __align__(16) u16 Xs[64 * LDM];   // x  [p][l_local]
  __shared__ float wl[256];
  const int c = blockIdx.x, h = blockIdx.y;
  const int tid = threadIdx.x;
  const int lane = tid & 63, w = tid >> 6;
  const int fr = lane & 15, q = lane >> 4;
  {
    float calast = cA2[h * 2048 + c * 256 + 255];
    float ca = cA2[h * 2048 + c * 256 + tid];
    wl[tid] = __expf(calast - ca) * dt2[h * 2048 + c * 256 + tid];
  }
  f32x4 acc[2][4];
#pragma unroll
  for (int i = 0; i < 2; ++i)
#pragma unroll
    for (int j = 0; j < 4; ++j) acc[i][j] = (f32x4){0.f, 0.f, 0.f, 0.f};

  const int lc8 = (tid & 7) * 8;
  const int rn = tid >> 3;   // 0..31
  __syncthreads();

  for (int kt = 0; kt < 4; ++kt) {
    __syncthreads();
#pragma unroll
    for (int r = 0; r < 4; ++r) {
      int n = rn + 32 * r;
      u16x8 raw = *(const u16x8*)(xT + (long)(4096 + n) * 2048 + c * 256 + kt * 64 + lc8);
      union { u16 u[8]; bf16x8 v; } pk;
#pragma unroll
      for (int u = 0; u < 8; ++u)
        pk.u[u] = f2bf(bf2f(raw[u]) * wl[kt * 64 + lc8 + u]);
      *(bf16x8*)(Ms + n * LDM + lc8) = pk.v;
    }
#pragma unroll
    for (int r = 0; r < 2; ++r) {
      int p = rn + 32 * r;
      *(bf16x8*)(Xs + p * LDM + lc8) =
          *(const bf16x8*)(xT + (long)(h * 64 + p) * 2048 + c * 256 + kt * 64 + lc8);
    }
    __syncthreads();
#pragma unroll
    for (int ks = 0; ks < 64; ks += 32) {
      bf16x8 af[2], xf[4];
#pragma unroll
      for (int i = 0; i < 2; ++i)
        af[i] = *(const bf16x8*)(Ms + (w * 32 + i * 16 + fr) * LDM + ks + q * 8);
#pragma unroll
      for (int j = 0; j < 4; ++j)
        xf[j] = *(const bf16x8*)(Xs + (j * 16 + fr) * LDM + ks + q * 8);
#pragma unroll
      for (int i = 0; i < 2; ++i)
#pragma unroll
        for (int j = 0; j < 4; ++j)
          acc[i][j] = __builtin_amdgcn_mfma_f32_16x16x32_bf16(af[i], xf[j], acc[i][j], 0, 0, 0);
    }
  }
  const int cr = (lane >> 4) * 4;
  const int cc = lane & 15;
  float* outp = stT + (long)(c * 64 + h) * 8192;
#pragma unroll
  for (int i = 0; i < 2; ++i)
#pragma unroll
    for (int j = 0; j < 4; ++j) {
      int n = w * 32 + i * 16 + cr;
      int p = j * 16 + cc;
#pragma unroll
      for (int t = 0; t < 4; ++t) outp[(n + t) * 64 + p] = acc[i][j][t];
    }
}

// ---------- 8-chunk inter-chunk scan ----------
__global__ __launch_bounds__(256) void scan_kernel(const float* __restrict__ stT,
                                                   const float* __restrict__ cA2,
                                                   float* __restrict__ prevT) {
  int id = blockIdx.x * 256 + threadIdx.x;   // h*8192 + n*64 + p
  int h = id >> 13;
  float acc = 0.f;
#pragma unroll
  for (int c = 0; c < NC; ++c) {
    prevT[(long)c * 524288 + id] = acc;
    float cd = __expf(cA2[h * 2048 + c * 256 + 255]);
    acc = acc * cd + stT[(long)c * 524288 + id];
  }
}

// ---------- intra+inter SSM output via bf16 MFMA ----------
__global__ __launch_bounds__(256) void ssm_y_kernel(const u16* __restrict__ xbf,
                                                    const u16* __restrict__ xT,
                                                    const float* __restrict__ dt2,
                                                    const float* __restrict__ cA2,
                                                    const float* __restrict__ CB,
                                                    const float* __restrict__ prevT,
                                                    const float* __restrict__ Dp,
                                                    u16* __restrict__ Y) {
  __shared__ __align__(16) u16 Ms[256 * LDM];
  __shared__ __align__(16) u16 Xt[64 * LDM];
  __shared__ float cas[256];
  __shared__ float dts[256];
  const int c = blockIdx.x, h = blockIdx.y;
  const int tid = threadIdx.x;
  const int lane = tid & 63;
  const int w = tid >> 6;
  const int fr = lane & 15, q = lane >> 4;

  cas[tid] = cA2[h * 2048 + c * 256 + tid];
  dts[tid] = dt2[h * 2048 + c * 256 + tid];

  f32x4 acc[4][4];
#pragma unroll
  for (int i = 0; i < 4; ++i)
#pragma unroll
    for (int j = 0; j < 4; ++j) acc[i][j] = (f32x4){0.f, 0.f, 0.f, 0.f};

  const int sg = (tid & 7) * 8;
  const int lb = tid >> 3;
  const int xp = tid & 63;
  const int xq = tid >> 6;

  __syncthreads();

  for (int kt = 0; kt < 6; ++kt) {
    __syncthreads();
    if (kt < 4) {
      const int s0 = kt * 64;
      f32x4 e0 = *(const f32x4*)&cas[s0 + sg];
      f32x4 e1 = *(const f32x4*)&cas[s0 + sg + 4];
      f32x4 d0 = *(const f32x4*)&dts[s0 + sg];
      f32x4 d1 = *(const f32x4*)&dts[s0 + sg + 4];
#pragma unroll
      for (int k = 0; k < 8; ++k) {
        const int l = lb + 32 * k;
        const float cal = cas[l];
        const float* cb = CB + (long)c * 65536 + (long)l * 256 + s0 + sg;
        f32x4 c0 = *(const f32x4*)cb;
        f32x4 c1 = *(const f32x4*)(cb + 4);
        union { u16 u[8]; bf16x8 v; } pk;
#pragma unroll
        for (int u = 0; u < 8; ++u) {
          int s = s0 + sg + u;
          float cv = (u < 4) ? c0[u] : c1[u - 4];
          float cs = (u < 4) ? e0[u] : e1[u - 4];
          float dv = (u < 4) ? d0[u] : d1[u - 4];
          float m = (s <= l) ? cv * __expf(cal - cs) * dv : 0.f;
          pk.u[u] = f2bf(m);
        }
        *(bf16x8*)(Ms + l * LDM + sg) = pk.v;
      }
#pragma unroll
      for (int r = 0; r < 2; ++r) {
        int p = (tid >> 3) + 32 * r;
        *(bf16x8*)(Xt + p * LDM + sg) =
            *(const bf16x8*)(xT + (long)(h * 64 + p) * 2048 + c * 256 + s0 + sg);
      }
    } else {
      const int n0 = (kt - 4) * 64;
#pragma unroll
      for (int k = 0; k < 8; ++k) {
        const int l = lb + 32 * k;
        const float ea = __expf(cas[l]);
        u16x8 raw = *(const u16x8*)(xbf + (long)(c * 256 + l) * CONVD + 4224 + n0 + sg);
        union { u16 u[8]; bf16x8 v; } pk;
#pragma unroll
        for (int u = 0; u < 8; ++u) pk.u[u] = f2bf(ea * bf2f(raw[u]));
        *(bf16x8*)(Ms + l * LDM + sg) = pk.v;
      }
      const float* pT = prevT + (long)(c * 64 + h) * 8192;
#pragma unroll
      for (int half = 0; half < 2; ++half) {
        const int nb2 = xq * 16 + half * 8;
        union { u16 u[8]; bf16x8 v; } pk;
#pragma unroll
        for (int u = 0; u < 8; ++u) pk.u[u] = f2bf(pT[(n0 + nb2 + u) * 64 + xp]);
        *(bf16x8*)(Xt + xp * LDM + nb2) = pk.v;
      }
    }
    __syncthreads();
#pragma unroll
    for (int ks = 0; ks < 64; ks += 32) {
      bf16x8 af[4], bfv[4];
#pragma unroll
      for (int i = 0; i < 4; ++i)
        af[i] = *(const bf16x8*)(Ms + (w * 64 + i * 16 + fr) * LDM + ks + q * 8);
#pragma unroll
      for (int j = 0; j < 4; ++j)
        bfv[j] = *(const bf16x8*)(Xt + (j * 16 + fr) * LDM + ks + q * 8);
#pragma unroll
      for (int i = 0; i < 4; ++i)
#pragma unroll
        for (int j = 0; j < 4; ++j)
          acc[i][j] = __builtin_amdgcn_mfma_f32_16x16x32_bf16(af[i], bfv[j], acc[i][j], 0, 0, 0);
    }
  }

  const int cr = (lane >> 4) * 4;
  const int cc = lane & 15;
  const float dh = Dp[h];
#pragma unroll
  for (int i = 0; i < 4; ++i)
#pragma unroll
    for (int j = 0; j < 4; ++j) {
      const int p = j * 16 + cc;
#pragma unroll
      for (int t = 0; t < 4; ++t) {
        const int row = w * 64 + i * 16 + cr + t;
        const float xv = bf2f(xbf[(long)(c * 256 + row) * CONVD + h * 64 + p]);
        Y[(long)(c * 256 + row) * 4096 + h * 64 + p] = f2bf(acc[i][j][t] + dh * xv);
      }
    }
}

// ---------- gated RMSNorm (Y bf16, gate bf16 from pb) -> bf16 z ----------
__global__ __launch_bounds__(256) void rmsnorm_kernel(const u16* __restrict__ Y,
                                                      const u16* __restrict__ pb,
                                                      const float* __restrict__ nw,
                                                      u16* __restrict__ zbf) {
  __shared__ float red[256];
  int t = blockIdx.x, tid = threadIdx.x;
  const u16* y = Y + (long)t * 4096;
  const u16* g = pb + (long)t * 8192;
  float zv[16];
  float s = 0.f;
#pragma unroll
  for (int k = 0; k < 16; ++k) {
    int i = tid + k * 256;
    float gv = bf2f(g[i]);
    float z = bf2f(y[i]) * (gv / (1.f + __expf(-gv)));
    zv[k] = z;
    s += z * z;
  }
  red[tid] = s;
  __syncthreads();
  if (tid < 128) red[tid] += red[tid + 128];
  __syncthreads();
  if (tid < 64) {
    float v = red[tid] + red[tid + 64];
    v += __shfl_down(v, 32);
    v += __shfl_down(v, 16);
    v += __shfl_down(v, 8);
    v += __shfl_down(v, 4);
    v += __shfl_down(v, 2);
    v += __shfl_down(v, 1);
    if (tid == 0) red[0] = v;
  }
  __syncthreads();
  float scale = rsqrtf(red[0] * (1.f / 4096.f) + 1e-5f);
#pragma unroll
  for (int k = 0; k < 16; ++k) {
    int i = tid + k * 256;
    zbf[(long)t * 4096 + i] = f2bf(zv[k] * scale * nw[i]);
  }
}

// ---------- launch ----------
extern "C" void kernel_launch(void* const* d_in, const int* in_sizes, int n_in,
                              void* d_out, int out_size, void* d_ws, size_t ws_size,
                              hipStream_t stream) {
  const float* hidden = (const float*)d_in[0];
  const float* Win    = (const float*)d_in[1];
  const float* convw  = (const float*)d_in[2];
  const float* convb  = (const float*)d_in[3];
  const float* dtb    = (const float*)d_in[4];
  const float* Ap     = (const float*)d_in[5];
  const float* Dp     = (const float*)d_in[6];
  const float* nw     = (const float*)d_in[7];
  const float* Wout   = (const float*)d_in[8];
  float* out = (float*)d_out;
  char* ws = (char*)d_ws;

  // workspace layout (bytes)
  u16*   hb    = (u16*)(ws + 0);            //  8,388,608
  u16*   WinT  = (u16*)(ws + 8388608L);     // 35,127,296  [8576][2048] bf16
  u16*   pb    = (u16*)(ws + 43515904L);    // 33,554,432  [2048][8192] bf16 (gate+x)
  float* ps    = (float*)(ws + 77070336L);  //  3,145,728  [2048][384] f32 (B/C/dt)
  u16*   WoutT = (u16*)(ws + 113770496L);   // 16,777,216  [2048][4096] bf16
  u16*   xbf   = (u16*)(ws + 130547712L);   // 17,825,792  [2048][4352] bf16
  u16*   xT    = (u16*)(ws + 148373504L);   // 17,301,504  [4224][2048] bf16
  float* dt2   = (float*)(ws + 165675008L); //    524,288  [64][2048]
  float* cA2   = (float*)(ws + 166199296L); //    524,288  [64][2048]
  float* CBv   = (float*)(ws + 166723584L); //  2,097,152  [8][256][256]
  float* stT   = (float*)(ws + 168820736L); // 16,777,216  [8][64][128][64]
  float* prevT = (float*)(ws + 185597952L); // 16,777,216
  u16*   zbf   = (u16*)(ws + 202375168L);   // 16,777,216  [2048][4096] bf16
  u16*   Y     = (u16*)(ws + 0);            // 16,777,216  bf16 (overlay hb+WinT, dead)
  float* Cp    = (float*)(ws + 43515904L);  // 67,108,864  out-proj partials x4 (overlay pb/ps, dead post-rmsnorm)
  float* Cs    = (float*)(ws + 168820736L); // 12,582,912  strip partials x4 (overlay stT, dead here)

  cvt_bf16<<<4096, 256, 0, stream>>>(hidden, hb, 1048576);
  transpose_bf16<<<dim3(134, 32), 256, 0, stream>>>(Win, WinT, 2048, 8512);
  transpose_bf16<<<dim3(32, 64), 256, 0, stream>>>(Wout, WoutT, 4096, 2048);
  // in-proj main: gate+x cols [0,8192) -> pb bf16; 8x32 tiles of 256^2, 256 blocks
  gemm256<1><<<dim3(32, 8, 1), 512, 0, stream>>>(hb, WinT, pb, 8192, 2048, 2048, 0L);
  // in-proj strip: B/C/dt cols [8192,8576) f32, split-K4 (192 blocks of K=512) + add
  gemm_bt<<<dim3(3, 16, 4), 256, 0, stream>>>(hb, WinT + 8192L * 2048, Cs,
                                              384, 2048, 512, 786432L);
  strip_add<<<768, 256, 0, stream>>>(Cs, ps);
  conv_silu_t<<<dim3(136, 64), 256, 0, stream>>>(pb, ps, convw, convb, xbf, xT);
  dt_cumsum<<<dim3(8, 64), 256, 0, stream>>>(ps, dtb, Ap, dt2, cA2);
  cb_gemm<<<dim3(2, 2, 8), 256, 0, stream>>>(xbf, CBv);
  states_kernel<<<dim3(8, 64), 256, 0, stream>>>(xT, dt2, cA2, stT);
  scan_kernel<<<2048, 256, 0, stream>>>(stT, cA2, prevT);
  ssm_y_kernel<<<dim3(8, 64), 256, 0, stream>>>(xbf, xT, dt2, cA2, CBv, prevT, Dp, Y);
  rmsnorm_kernel<<<2048, 256, 0, stream>>>(Y, pb, nw, zbf);
  // out-proj: 8x8 tiles x split-K4 = 256 blocks, f32 partials + add4
  gemm256<0><<<dim3(8, 8, 4), 512, 0, stream>>>(zbf, WoutT, Cp, 2048, 4096, 1024, 4194304L);
  add4_kernel<<<4096, 256, 0, stream>>>(Cp, out);
}

// Round 8
// 387.417 us; speedup vs baseline: 1.1498x; 1.0046x over previous
//
#include <hip/hip_runtime.h>

// ---------- types ----------
typedef __bf16 bf16_t;
typedef bf16_t bf16x8 __attribute__((ext_vector_type(8)));
typedef float f32x4 __attribute__((ext_vector_type(4)));
typedef unsigned short u16;
typedef u16 u16x8 __attribute__((ext_vector_type(8)));
typedef u16 u16x4 __attribute__((ext_vector_type(4)));

// ---------- model dims ----------
#define SEQ   2048
#define HID   2048
#define INTER 4096
#define NH    64
#define HD    64
#define CONVD 4352
#define DIN   8512
#define CHNK  256
#define NC    8

__device__ __forceinline__ u16 f2bf(float f) {
  union { float f; unsigned u; } a; a.f = f;
  return (u16)((a.u + 0x7fffu + ((a.u >> 16) & 1u)) >> 16);
}
__device__ __forceinline__ float bf2f(u16 u) {
  union { unsigned u; float f; } a; a.u = ((unsigned)u) << 16;
  return a.f;
}

__device__ __forceinline__ void gl2lds16(const void* g, void* l) {
  auto gp = reinterpret_cast<__attribute__((address_space(1))) void*>(
      (unsigned long long)g);
  auto lp = reinterpret_cast<__attribute__((address_space(3))) void*>(
      (unsigned)(unsigned long long)l);
  __builtin_amdgcn_global_load_lds(gp, lp, 16, 0, 0);
}

// forced-register LDS vector read
__device__ __forceinline__ bf16x8 ds128(unsigned addr) {
  bf16x8 r;
  asm volatile("ds_read_b128 %0, %1" : "=v"(r) : "v"(addr));
  return r;
}

// ---------- fp32 -> bf16 flat convert (vectorized, n4 = n/4) ----------
__global__ __launch_bounds__(256) void cvt_bf16(const float* __restrict__ s,
                                                u16* __restrict__ d, int n4) {
  int i = blockIdx.x * 256 + threadIdx.x;
  if (i < n4) {
    f32x4 v = ((const f32x4*)s)[i];
    u16x4 r;
#pragma unroll
    for (int k = 0; k < 4; ++k) r[k] = f2bf(v[k]);
    ((u16x4*)d)[i] = r;
  }
}

// ---------- transpose + convert: src[R][Cc] f32 -> dst[n][R] bf16, 64x64 tiles ----------
__global__ __launch_bounds__(256) void transpose_bf16(const float* __restrict__ src,
                                                      u16* __restrict__ dst,
                                                      int R, int Cc) {
  __shared__ u16 t[64][72];
  const int n0 = blockIdx.x * 64, k0 = blockIdx.y * 64;
  const int tx = threadIdx.x & 15;   // n/4 group
  const int ty = threadIdx.x >> 4;   // k row base
  if (n0 + 63 < Cc) {
#pragma unroll
    for (int j = 0; j < 4; ++j) {
      int k = ty + j * 16;
      f32x4 v = *(const f32x4*)(src + (long)(k0 + k) * Cc + n0 + tx * 4);
#pragma unroll
      for (int e = 0; e < 4; ++e) t[tx * 4 + e][k] = f2bf(v[e]);
    }
  } else {
#pragma unroll
    for (int j = 0; j < 4; ++j) {
      int k = ty + j * 16;
#pragma unroll
      for (int e = 0; e < 4; ++e) {
        int n = n0 + tx * 4 + e;
        t[tx * 4 + e][k] = (n < Cc) ? f2bf(src[(long)(k0 + k) * Cc + n]) : (u16)0;
      }
    }
  }
  __syncthreads();
  const int cg = threadIdx.x & 7;
  const int r0 = threadIdx.x >> 3;   // 0..31
#pragma unroll
  for (int j = 0; j < 2; ++j) {
    int row = r0 + j * 32;
    u16x8 o;
#pragma unroll
    for (int e = 0; e < 8; ++e) o[e] = t[row][cg * 8 + e];
    *(u16x8*)(dst + (long)(n0 + row) * R + k0 + cg * 8) = o;
  }
}

// ---------- bf16 MFMA GEMM: 128x128 tile, BK=64 (384-col strip, f32 out) ----------
__global__ __launch_bounds__(256, 2) void gemm_bt(const u16* __restrict__ A,
                                                  const u16* __restrict__ Bt,
                                                  float* __restrict__ C,
                                                  int N, int lda, int Klen,
                                                  long zstride) {
  __shared__ __align__(16) u16 As[128 * 64];
  __shared__ __align__(16) u16 Bs[128 * 64];
  const int kz = blockIdx.z;
  A  += (long)kz * Klen;
  Bt += (long)kz * Klen;
  C  += (long)kz * zstride;
  const int nb = gridDim.x * gridDim.y;
  const int id = blockIdx.x + gridDim.x * blockIdx.y;
  const int s = (id & 7) * (nb >> 3) + (id >> 3);
  const long bm = s & 15;
  const long bn = s >> 4;

  const int tid = threadIdx.x;
  const int lane = tid & 63;
  const int w = tid >> 6;
  const int wm = w >> 1, wn = w & 1;

  f32x4 acc[4][4];
#pragma unroll
  for (int i = 0; i < 4; ++i)
#pragma unroll
    for (int j = 0; j < 4; ++j) acc[i][j] = (f32x4){0.f, 0.f, 0.f, 0.f};

  const int srr = lane >> 3;
  const int sc8 = ((lane & 7) ^ srr) * 8;
  const u16* Agw = A + (bm * 128 + w * 8 + srr) * (long)lda + sc8;
  const u16* Bgw = Bt + (bn * 128 + w * 8 + srr) * (long)lda + sc8;
  u16* ldA = As + w * 512 + lane * 8;
  u16* ldB = Bs + w * 512 + lane * 8;
  const int fr = lane & 15, q = lane >> 4;
  const int fx = (fr & 7) << 3;

  for (int k0 = 0; k0 < Klen; k0 += 64) {
    __syncthreads();
#pragma unroll
    for (int t = 0; t < 4; ++t) {
      gl2lds16(Agw + k0 + (long)t * 32 * lda, ldA + t * 2048);
      gl2lds16(Bgw + k0 + (long)t * 32 * lda, ldB + t * 2048);
    }
    __builtin_amdgcn_s_waitcnt(0);
    __syncthreads();
#pragma unroll
    for (int ks = 0; ks < 2; ++ks) {
      bf16x8 af[4], bfv[4];
#pragma unroll
      for (int i = 0; i < 4; ++i)
        af[i] = *(const bf16x8*)(As + ((wm * 64 + i * 16 + fr) << 6) +
                                 ((((ks << 2) + q) << 3) ^ fx));
#pragma unroll
      for (int j = 0; j < 4; ++j)
        bfv[j] = *(const bf16x8*)(Bs + ((wn * 64 + j * 16 + fr) << 6) +
                                  ((((ks << 2) + q) << 3) ^ fx));
#pragma unroll
      for (int i = 0; i < 4; ++i)
#pragma unroll
        for (int j = 0; j < 4; ++j)
          acc[i][j] = __builtin_amdgcn_mfma_f32_16x16x32_bf16(af[i], bfv[j], acc[i][j], 0, 0, 0);
    }
  }
  const int cr = (lane >> 4) * 4;
  const int cc = lane & 15;
#pragma unroll
  for (int i = 0; i < 4; ++i)
#pragma unroll
    for (int j = 0; j < 4; ++j) {
      long r = bm * 128 + wm * 64 + i * 16 + cr;
      long cidx = bn * 128 + wn * 64 + j * 16 + cc;
      float* cp = C + r * (long)N + cidx;
#pragma unroll
      for (int t = 0; t < 4; ++t) cp[(long)t * N] = acc[i][j][t];
    }
}

// ============================================================================
// 256x256-tile 8-phase bf16 MFMA GEMM, BK=64, 512 threads (verified schedule).
// BFOUT=1 -> bf16 output, BFOUT=0 -> f32.
// ============================================================================
#define MFMA16(ACC, AF, BF)                                                    \
  _Pragma("unroll") for (int i_ = 0; i_ < 4; ++i_)                             \
  _Pragma("unroll") for (int j_ = 0; j_ < 2; ++j_) {                           \
    ACC[i_][j_] = __builtin_amdgcn_mfma_f32_16x16x32_bf16(                     \
        AF[i_][0], BF[j_][0], ACC[i_][j_], 0, 0, 0);                           \
    ACC[i_][j_] = __builtin_amdgcn_mfma_f32_16x16x32_bf16(                     \
        AF[i_][1], BF[j_][1], ACC[i_][j_], 0, 0, 0);                           \
  }

#define LDAF(DST, SLOT)                                                        \
  {                                                                            \
    unsigned ab_ = (unsigned)(unsigned long long)(&Abuf[SLOT][0]);             \
    _Pragma("unroll") for (int i_ = 0; i_ < 4; ++i_) {                         \
      unsigned ro_ = ab_ + (((wm * 64 + i_ * 16 + fr) << 6) << 1);             \
      DST[i_][0] = ds128(ro_ + (ke0 << 1));                                    \
      DST[i_][1] = ds128(ro_ + (ke1 << 1));                                    \
    }                                                                          \
  }

#define LDBF(DST, SLOT)                                                        \
  {                                                                            \
    unsigned bb_ = (unsigned)(unsigned long long)(&Bbuf[SLOT][0]);             \
    _Pragma("unroll") for (int j_ = 0; j_ < 2; ++j_) {                         \
      unsigned ro_ = bb_ + (((wn * 32 + j_ * 16 + fr) << 6) << 1);             \
      DST[j_][0] = ds128(ro_ + (ke0 << 1));                                    \
      DST[j_][1] = ds128(ro_ + (ke1 << 1));                                    \
    }                                                                          \
  }

#define STAGE(G, HO, KO, SLOT, BUF)                                            \
  {                                                                            \
    const u16* g_ = (G) + (HO) + (KO);                                         \
    gl2lds16(g_ + off1, BUF[SLOT] + lo1);                                      \
    gl2lds16(g_ + off2, BUF[SLOT] + lo2);                                      \
  }

#define PH_FENCE()                                                             \
  asm volatile("s_waitcnt lgkmcnt(0)" ::: "memory");                           \
  __builtin_amdgcn_sched_barrier(0);

template <int BFOUT>
__global__ __launch_bounds__(512, 2) void gemm256(const u16* __restrict__ A,
                                                  const u16* __restrict__ Bt,
                                                  void* __restrict__ Cv,
                                                  int N, int lda, int Klen,
                                                  long zstride) {
  __shared__ __align__(16) u16 Abuf[4][128 * 64];
  __shared__ __align__(16) u16 Bbuf[4][128 * 64];

  const int kz = blockIdx.z;
  A  += (long)kz * Klen;
  Bt += (long)kz * Klen;
  const long czoff = (long)kz * zstride;

  // XCD-contiguous remap (nb % 8 == 0)
  const int nb = gridDim.x * gridDim.y;
  const int id = blockIdx.x + gridDim.x * blockIdx.y;
  const int s = (id & 7) * (nb >> 3) + (id >> 3);
  const long bm = s & 7;
  const long bn = s >> 3;

  const int tid = threadIdx.x;
  const int lane = tid & 63;
  const int w = tid >> 6;        // wave 0..7
  const int wm = w >> 2;         // 0..1
  const int wn = w & 3;          // 0..3
  const int fr = lane & 15, q = lane >> 4;
  const int ke0 = (q ^ (fr & 7)) << 3;
  const int ke1 = ((4 + q) ^ (fr & 7)) << 3;

  const int sr1 = (w << 4) + (lane >> 3);
  const int sr2 = sr1 + 8;
  const int kcp = lane & 7;
  const long off1 = (long)sr1 * lda + ((kcp ^ (sr1 & 7)) << 3);
  const long off2 = (long)sr2 * lda + ((kcp ^ (sr2 & 7)) << 3);
  const int lo1 = (w << 10) + (lane << 3);
  const int lo2 = lo1 + 512;
  const long h128 = 128L * lda;

  const u16* gA = A + bm * 256 * lda;
  const u16* gB = Bt + bn * 256 * lda;

  f32x4 acc00[4][2], acc01[4][2], acc10[4][2], acc11[4][2];
#pragma unroll
  for (int i = 0; i < 4; ++i)
#pragma unroll
    for (int j = 0; j < 2; ++j) {
      acc00[i][j] = (f32x4){0.f, 0.f, 0.f, 0.f};
      acc01[i][j] = (f32x4){0.f, 0.f, 0.f, 0.f};
      acc10[i][j] = (f32x4){0.f, 0.f, 0.f, 0.f};
      acc11[i][j] = (f32x4){0.f, 0.f, 0.f, 0.f};
    }

  const int NT = Klen >> 6;

  // ---- prologue: stage tiles 0 and 1 fully ----
  STAGE(gA, 0L, 0L, 0, Abuf);
  STAGE(gB, 0L, 0L, 0, Bbuf);
  STAGE(gB, h128, 0L, 1, Bbuf);
  STAGE(gA, h128, 0L, 1, Abuf);
  STAGE(gA, 0L, 64L, 2, Abuf);
  STAGE(gB, 0L, 64L, 2, Bbuf);
  STAGE(gB, h128, 64L, 3, Bbuf);
  STAGE(gA, h128, 64L, 3, Abuf);
  asm volatile("s_waitcnt vmcnt(8)" ::: "memory");
  __builtin_amdgcn_s_barrier();

  for (int T = 0; T < NT; ++T) {
    const int t2 = (T << 1) & 3;
    const int t2p1 = (t2 + 1) & 3;
    const long kT2 = (long)(T + 2) << 6;
    const bool g2 = (T + 2 < NT);
    bf16x8 a0[4][2], a1[4][2], b0[2][2], b1[2][2];

    // ---- phase 1: quadrant (A0,B0) ----
    LDAF(a0, t2);
    LDBF(b0, t2);
    asm volatile("s_waitcnt lgkmcnt(8)" ::: "memory");
    __builtin_amdgcn_s_barrier();
    PH_FENCE();
    __builtin_amdgcn_s_setprio(1);
    MFMA16(acc00, a0, b0);
    __builtin_amdgcn_s_setprio(0);
    __builtin_amdgcn_s_barrier();

    // ---- phase 2: quadrant (A0,B1); stage A0(T+2) ----
    LDBF(b1, t2p1);
    if (g2) STAGE(gA, 0L, kT2, t2, Abuf);
    __builtin_amdgcn_s_barrier();
    PH_FENCE();
    __builtin_amdgcn_s_setprio(1);
    MFMA16(acc01, a0, b1);
    __builtin_amdgcn_s_setprio(0);
    __builtin_amdgcn_s_barrier();

    // ---- phase 3: quadrant (A1,B0); stage B0(T+2) ----
    LDAF(a1, t2p1);
    if (g2) STAGE(gB, 0L, kT2, t2, Bbuf);
    __builtin_amdgcn_s_barrier();
    PH_FENCE();
    __builtin_amdgcn_s_setprio(1);
    MFMA16(acc10, a1, b0);
    __builtin_amdgcn_s_setprio(0);
    __builtin_amdgcn_s_barrier();

    // ---- phase 4: quadrant (A1,B1); stage B1+A1(T+2); single wait ----
    if (g2) {
      STAGE(gB, h128, kT2, t2p1, Bbuf);
      STAGE(gA, h128, kT2, t2p1, Abuf);
    }
    __builtin_amdgcn_s_barrier();
    PH_FENCE();
    __builtin_amdgcn_s_setprio(1);
    MFMA16(acc11, a1, b1);
    __builtin_amdgcn_s_setprio(0);
    if (g2)
      asm volatile("s_waitcnt vmcnt(8)" ::: "memory");
    else
      asm volatile("s_waitcnt vmcnt(0)" ::: "memory");
    __builtin_amdgcn_s_barrier();
  }

  // ---- epilogue: C write, col-guarded; bf16 or f32 per BFOUT ----
  const int cr = (lane >> 4) << 2;
  const int cc = lane & 15;
  const long r0 = bm * 256 + wm * 64 + cr;
  const long c0 = bn * 256 + wn * 32 + cc;
#define CWRITE(ACC, QA, QB)                                                    \
  _Pragma("unroll") for (int i_ = 0; i_ < 4; ++i_)                             \
  _Pragma("unroll") for (int j_ = 0; j_ < 2; ++j_) {                           \
    long r_ = r0 + (QA)*128 + i_ * 16;                                         \
    long c_ = c0 + (QB)*128 + j_ * 16;                                         \
    if (c_ < N) {                                                              \
      long base_ = czoff + r_ * (long)N + c_;                                  \
      _Pragma("unroll") for (int t_ = 0; t_ < 4; ++t_) {                       \
        if (BFOUT)                                                             \
          ((u16*)Cv)[base_ + (long)t_ * N] = f2bf(ACC[i_][j_][t_]);            \
        else                                                                   \
          ((float*)Cv)[base_ + (long)t_ * N] = ACC[i_][j_][t_];                \
      }                                                                        \
    }                                                                          \
  }
  CWRITE(acc00, 0, 0)
  CWRITE(acc01, 0, 1)
  CWRITE(acc10, 1, 0)
  CWRITE(acc11, 1, 1)
#undef CWRITE
}

// ---------- split-K-4 partial add: out = p0+p1+p2+p3 (compact [2048][4096]) ----------
__global__ __launch_bounds__(256) void add4_kernel(const float* __restrict__ a,
                                                   float* __restrict__ o) {
  int i = blockIdx.x * 256 + threadIdx.x;
  f32x4 r = ((const f32x4*)a)[i];
  r += ((const f32x4*)(a + 4194304L))[i];
  r += ((const f32x4*)(a + 8388608L))[i];
  r += ((const f32x4*)(a + 12582912L))[i];
  ((f32x4*)o)[i] = r;
}

// ---------- fused depthwise conv (K=4) + SiLU -> xbf AND xT (transposed) ----------
// x region (cols<4096) read from bf16 pb; B/C region summed from 4 strip partials.
__global__ __launch_bounds__(256) void conv_silu_t(const u16* __restrict__ pb,
                                                   const float* __restrict__ Cs,
                                                   const float* __restrict__ cw,
                                                   const float* __restrict__ cb,
                                                   u16* __restrict__ xbf,
                                                   u16* __restrict__ xT) {
  __shared__ float ld[35][33];
  __shared__ u16 tt[32][34];
  const int c0 = blockIdx.x * 32, t0 = blockIdx.y * 32;
  const int tx = threadIdx.x & 31, ty = threadIdx.x >> 5;
  const bool mainreg = (c0 < 4096);
  for (int i = ty; i < 35; i += 8) {
    int t = t0 - 3 + i;
    float v = 0.f;
    if (t >= 0) {
      if (mainreg) {
        v = bf2f(pb[(long)t * 8192 + 4096 + c0 + tx]);
      } else {
        long idx = (long)t * 384 + (c0 - 4096) + tx;
        v = Cs[idx];
        v += Cs[idx + 786432L];
        v += Cs[idx + 1572864L];
        v += Cs[idx + 2359296L];
      }
    }
    ld[i][tx] = v;
  }
  const int c = c0 + tx;
  const float w0 = cw[c * 4 + 0], w1 = cw[c * 4 + 1], w2 = cw[c * 4 + 2],
              w3 = cw[c * 4 + 3], bias = cb[c];
  __syncthreads();
  for (int i = ty; i < 32; i += 8) {
    float a = bias + w0 * ld[i][tx] + w1 * ld[i + 1][tx] + w2 * ld[i + 2][tx] +
              w3 * ld[i + 3][tx];
    u16 v = f2bf(a / (1.f + __expf(-a)));
    xbf[(long)(t0 + i) * CONVD + c] = v;
    tt[i][tx] = v;
  }
  __syncthreads();
  if (c0 < 4224) {   // x + B + C regions get transposed
    for (int i = ty; i < 32; i += 8)
      xT[(long)(c0 + i) * 2048 + t0 + tx] = tt[tx][i];
  }
}

// ---------- dt softplus + per-chunk cumsum (Hillis-Steele), [h][t] layout ----------
// dt read summed from the 4 strip partials directly (bit-exact vs strip_add).
__global__ __launch_bounds__(256) void dt_cumsum(const float* __restrict__ Cs,
                                                 const float* __restrict__ dtb,
                                                 const float* __restrict__ A,
                                                 float* __restrict__ dt2,
                                                 float* __restrict__ cA2) {
  __shared__ float sc[256];
  int c = blockIdx.x, h = blockIdx.y, l = threadIdx.x;
  long idx = (long)(c * 256 + l) * 384 + 256 + h;
  float v = Cs[idx];
  v += Cs[idx + 786432L];
  v += Cs[idx + 1572864L];
  v += Cs[idx + 2359296L];
  v += dtb[h];
  float sp = (v > 20.f) ? v : log1pf(__expf(v));
  dt2[h * 2048 + c * 256 + l] = sp;
  sc[l] = sp * A[h];
  __syncthreads();
  for (int off = 1; off < 256; off <<= 1) {
    float t = (l >= off) ? sc[l - off] : 0.f;
    __syncthreads();
    sc[l] += t;
    __syncthreads();
  }
  cA2[h * 2048 + c * 256 + l] = sc[l];
}

// ---------- CB[c][l][s] = C[l,:].B[s,:] via MFMA, per-chunk strided GEMM ----------
__global__ __launch_bounds__(256, 2) void cb_gemm(const u16* __restrict__ xbf,
                                                  float* __restrict__ CB) {
  __shared__ __align__(16) u16 As[128 * 32];
  __shared__ __align__(16) u16 Bs[128 * 32];
  const int tid = threadIdx.x;
  const int lane = tid & 63;
  const int w = tid >> 6;
  const int wm = w >> 1, wn = w & 1;
  const int bm = blockIdx.y, bn = blockIdx.x, c = blockIdx.z;

  f32x4 acc[4][4];
#pragma unroll
  for (int i = 0; i < 4; ++i)
#pragma unroll
    for (int j = 0; j < 4; ++j) acc[i][j] = (f32x4){0.f, 0.f, 0.f, 0.f};

  const int sr = w * 32 + (lane >> 2);
  const int sc = ((lane & 3) ^ ((lane >> 2) & 3)) * 8;
  const u16* Ag = xbf + (long)(c * 256 + bm * 128) * CONVD + 4224;  // C region
  const u16* Bg = xbf + (long)(c * 256 + bn * 128) * CONVD + 4096;  // B region
  u16* lA0 = As + w * 1024 + lane * 8;
  u16* lA1 = As + w * 1024 + 512 + lane * 8;
  u16* lB0 = Bs + w * 1024 + lane * 8;
  u16* lB1 = Bs + w * 1024 + 512 + lane * 8;
  const int fr = lane & 15, q = lane >> 4;
  const int pc = ((q ^ (fr & 3)) << 3);

  for (int k0 = 0; k0 < 128; k0 += 32) {
    __syncthreads();
    const u16* a0 = Ag + (long)sr * CONVD + k0 + sc;
    const u16* b0 = Bg + (long)sr * CONVD + k0 + sc;
    gl2lds16(a0, lA0);
    gl2lds16(a0 + 16L * CONVD, lA1);
    gl2lds16(b0, lB0);
    gl2lds16(b0 + 16L * CONVD, lB1);
    __builtin_amdgcn_s_waitcnt(0);
    __syncthreads();
    bf16x8 af[4], bfv[4];
#pragma unroll
    for (int i = 0; i < 4; ++i)
      af[i] = *(const bf16x8*)(As + ((wm * 64 + i * 16 + fr) << 5) + pc);
#pragma unroll
    for (int j = 0; j < 4; ++j)
      bfv[j] = *(const bf16x8*)(Bs + ((wn * 64 + j * 16 + fr) << 5) + pc);
#pragma unroll
    for (int i = 0; i < 4; ++i)
#pragma unroll
      for (int j = 0; j < 4; ++j)
        acc[i][j] = __builtin_amdgcn_mfma_f32_16x16x32_bf16(af[i], bfv[j], acc[i][j], 0, 0, 0);
  }
  const int cr = (lane >> 4) * 4;
  const int cc = lane & 15;
  float* Cc = CB + (long)c * 65536;
#pragma unroll
  for (int i = 0; i < 4; ++i)
#pragma unroll
    for (int j = 0; j < 4; ++j) {
      int r = bm * 128 + wm * 64 + i * 16 + cr;
      int cidx = bn * 128 + wn * 64 + j * 16 + cc;
      float* cp = Cc + (long)r * 256 + cidx;
#pragma unroll
      for (int t = 0; t < 4; ++t) cp[t * 256] = acc[i][j][t];
    }
}

// ---------- states via MFMA: stT[n][p] = sum_l (B[l][n]*wl[l]) * x[l][p] ----------
#define LDM 72
__global__ __launch_bounds__(256) void states_kernel(const u16* __restrict__ xT,
                                                     const float* __restrict__ dt2,
                                                     const float* __restrict__ cA2,
                                                     float* __restrict__ stT) {
  __shared__ __align__(16) u16 Ms[128 * LDM];  // Bw [n][l_local]
  __shared__ __align__(16) u16 Xs[64 * LDM];   // x  [p][l_local]
  __shared__ float wl[256];
  const int c = blockIdx.x, h = blockIdx.y;
  const int tid = threadIdx.x;
  const int lane = tid & 63, w = tid >> 6;
  const int fr = lane & 15, q = lane >> 4;
  {
    float calast = cA2[h * 2048 + c * 256 + 255];
    float ca = cA2[h * 2048 + c * 256 + tid];
    wl[tid] = __expf(calast - ca) * dt2[h * 2048 + c * 256 + tid];
  }
  f32x4 acc[2][4];
#pragma unroll
  for (int i = 0; i < 2; ++i)
#pragma unroll
    for (int j = 0; j < 4; ++j) acc[i][j] = (f32x4){0.f, 0.f, 0.f, 0.f};

  const int lc8 = (tid & 7) * 8;
  const int rn = tid >> 3;   // 0..31
  __syncthreads();

  for (int kt = 0; kt < 4; ++kt) {
    __syncthreads();
#pragma unroll
    for (int r = 0; r < 4; ++r) {
      int n = rn + 32 * r;
      u16x8 raw = *(const u16x8*)(xT + (long)(4096 + n) * 2048 + c * 256 + kt * 64 + lc8);
      union { u16 u[8]; bf16x8 v; } pk;
#pragma unroll
      for (int u = 0; u < 8; ++u)
        pk.u[u] = f2bf(bf2f(raw[u]) * wl[kt * 64 + lc8 + u]);
      *(bf16x8*)(Ms + n * LDM + lc8) = pk.v;
    }
#pragma unroll
    for (int r = 0; r < 2; ++r) {
      int p = rn + 32 * r;
      *(bf16x8*)(Xs + p * LDM + lc8) =
          *(const bf16x8*)(xT + (long)(h * 64 + p) * 2048 + c * 256 + kt * 64 + lc8);
    }
    __syncthreads();
#pragma unroll
    for (int ks = 0; ks < 64; ks += 32) {
      bf16x8 af[2], xf[4];
#pragma unroll
      for (int i = 0; i < 2; ++i)
        af[i] = *(const bf16x8*)(Ms + (w * 32 + i * 16 + fr) * LDM + ks + q * 8);
#pragma unroll
      for (int j = 0; j < 4; ++j)
        xf[j] = *(const bf16x8*)(Xs + (j * 16 + fr) * LDM + ks + q * 8);
#pragma unroll
      for (int i = 0; i < 2; ++i)
#pragma unroll
        for (int j = 0; j < 4; ++j)
          acc[i][j] = __builtin_amdgcn_mfma_f32_16x16x32_bf16(af[i], xf[j], acc[i][j], 0, 0, 0);
    }
  }
  const int cr = (lane >> 4) * 4;
  const int cc = lane & 15;
  float* outp = stT + (long)(c * 64 + h) * 8192;
#pragma unroll
  for (int i = 0; i < 2; ++i)
#pragma unroll
    for (int j = 0; j < 4; ++j) {
      int n = w * 32 + i * 16 + cr;
      int p = j * 16 + cc;
#pragma unroll
      for (int t = 0; t < 4; ++t) outp[(n + t) * 64 + p] = acc[i][j][t];
    }
}

// ---------- 8-chunk inter-chunk scan (bf16 prevT out; recurrence stays f32) ----------
__global__ __launch_bounds__(256) void scan_kernel(const float* __restrict__ stT,
                                                   const float* __restrict__ cA2,
                                                   u16* __restrict__ prevT) {
  int id = blockIdx.x * 256 + threadIdx.x;   // h*8192 + n*64 + p
  int h = id >> 13;
  float acc = 0.f;
#pragma unroll
  for (int c = 0; c < NC; ++c) {
    prevT[(long)c * 524288 + id] = f2bf(acc);
    float cd = __expf(cA2[h * 2048 + c * 256 + 255]);
    acc = acc * cd + stT[(long)c * 524288 + id];
  }
}

// ---------- intra+inter SSM output via bf16 MFMA ----------
__global__ __launch_bounds__(256) void ssm_y_kernel(const u16* __restrict__ xbf,
                                                    const u16* __restrict__ xT,
                                                    const float* __restrict__ dt2,
                                                    const float* __restrict__ cA2,
                                                    const float* __restrict__ CB,
                                                    const u16* __restrict__ prevT,
                                                    const float* __restrict__ Dp,
                                                    u16* __restrict__ Y) {
  __shared__ __align__(16) u16 Ms[256 * LDM];
  __shared__ __align__(16) u16 Xt[64 * LDM];
  __shared__ float cas[256];
  __shared__ float dts[256];
  const int c = blockIdx.x, h = blockIdx.y;
  const int tid = threadIdx.x;
  const int lane = tid & 63;
  const int w = tid >> 6;
  const int fr = lane & 15, q = lane >> 4;

  cas[tid] = cA2[h * 2048 + c * 256 + tid];
  dts[tid] = dt2[h * 2048 + c * 256 + tid];

  f32x4 acc[4][4];
#pragma unroll
  for (int i = 0; i < 4; ++i)
#pragma unroll
    for (int j = 0; j < 4; ++j) acc[i][j] = (f32x4){0.f, 0.f, 0.f, 0.f};

  const int sg = (tid & 7) * 8;
  const int lb = tid >> 3;
  const int xp = tid & 63;
  const int xq = tid >> 6;

  __syncthreads();

  for (int kt = 0; kt < 6; ++kt) {
    __syncthreads();
    if (kt < 4) {
      const int s0 = kt * 64;
      f32x4 e0 = *(const f32x4*)&cas[s0 + sg];
      f32x4 e1 = *(const f32x4*)&cas[s0 + sg + 4];
      f32x4 d0 = *(const f32x4*)&dts[s0 + sg];
      f32x4 d1 = *(const f32x4*)&dts[s0 + sg + 4];
#pragma unroll
      for (int k = 0; k < 8; ++k) {
        const int l = lb + 32 * k;
        const float cal = cas[l];
        const float* cb = CB + (long)c * 65536 + (long)l * 256 + s0 + sg;
        f32x4 c0 = *(const f32x4*)cb;
        f32x4 c1 = *(const f32x4*)(cb + 4);
        union { u16 u[8]; bf16x8 v; } pk;
#pragma unroll
        for (int u = 0; u < 8; ++u) {
          int s = s0 + sg + u;
          float cv = (u < 4) ? c0[u] : c1[u - 4];
          float cs = (u < 4) ? e0[u] : e1[u - 4];
          float dv = (u < 4) ? d0[u] : d1[u - 4];
          float m = (s <= l) ? cv * __expf(cal - cs) * dv : 0.f;
          pk.u[u] = f2bf(m);
        }
        *(bf16x8*)(Ms + l * LDM + sg) = pk.v;
      }
#pragma unroll
      for (int r = 0; r < 2; ++r) {
        int p = (tid >> 3) + 32 * r;
        *(bf16x8*)(Xt + p * LDM + sg) =
            *(const bf16x8*)(xT + (long)(h * 64 + p) * 2048 + c * 256 + s0 + sg);
      }
    } else {
      const int n0 = (kt - 4) * 64;
#pragma unroll
      for (int k = 0; k < 8; ++k) {
        const int l = lb + 32 * k;
        const float ea = __expf(cas[l]);
        u16x8 raw = *(const u16x8*)(xbf + (long)(c * 256 + l) * CONVD + 4224 + n0 + sg);
        union { u16 u[8]; bf16x8 v; } pk;
#pragma unroll
        for (int u = 0; u < 8; ++u) pk.u[u] = f2bf(ea * bf2f(raw[u]));
        *(bf16x8*)(Ms + l * LDM + sg) = pk.v;
      }
      const u16* pT = prevT + (long)(c * 64 + h) * 8192;
#pragma unroll
      for (int half = 0; half < 2; ++half) {
        const int nb2 = xq * 16 + half * 8;
        union { u16 u[8]; bf16x8 v; } pk;
#pragma unroll
        for (int u = 0; u < 8; ++u) pk.u[u] = pT[(n0 + nb2 + u) * 64 + xp];
        *(bf16x8*)(Xt + xp * LDM + nb2) = pk.v;
      }
    }
    __syncthreads();
#pragma unroll
    for (int ks = 0; ks < 64; ks += 32) {
      bf16x8 af[4], bfv[4];
#pragma unroll
      for (int i = 0; i < 4; ++i)
        af[i] = *(const bf16x8*)(Ms + (w * 64 + i * 16 + fr) * LDM + ks + q * 8);
#pragma unroll
      for (int j = 0; j < 4; ++j)
        bfv[j] = *(const bf16x8*)(Xt + (j * 16 + fr) * LDM + ks + q * 8);
#pragma unroll
      for (int i = 0; i < 4; ++i)
#pragma unroll
        for (int j = 0; j < 4; ++j)
          acc[i][j] = __builtin_amdgcn_mfma_f32_16x16x32_bf16(af[i], bfv[j], acc[i][j], 0, 0, 0);
    }
  }

  const int cr = (lane >> 4) * 4;
  const int cc = lane & 15;
  const float dh = Dp[h];
#pragma unroll
  for (int i = 0; i < 4; ++i)
#pragma unroll
    for (int j = 0; j < 4; ++j) {
      const int p = j * 16 + cc;
#pragma unroll
      for (int t = 0; t < 4; ++t) {
        const int row = w * 64 + i * 16 + cr + t;
        const float xv = bf2f(xbf[(long)(c * 256 + row) * CONVD + h * 64 + p]);
        Y[(long)(c * 256 + row) * 4096 + h * 64 + p] = f2bf(acc[i][j][t] + dh * xv);
      }
    }
}

// ---------- gated RMSNorm (Y bf16, gate bf16 from pb) -> bf16 z ----------
__global__ __launch_bounds__(256) void rmsnorm_kernel(const u16* __restrict__ Y,
                                                      const u16* __restrict__ pb,
                                                      const float* __restrict__ nw,
                                                      u16* __restrict__ zbf) {
  __shared__ float red[256];
  int t = blockIdx.x, tid = threadIdx.x;
  const u16* y = Y + (long)t * 4096;
  const u16* g = pb + (long)t * 8192;
  float zv[16];
  float s = 0.f;
#pragma unroll
  for (int k = 0; k < 16; ++k) {
    int i = tid + k * 256;
    float gv = bf2f(g[i]);
    float z = bf2f(y[i]) * (gv / (1.f + __expf(-gv)));
    zv[k] = z;
    s += z * z;
  }
  red[tid] = s;
  __syncthreads();
  if (tid < 128) red[tid] += red[tid + 128];
  __syncthreads();
  if (tid < 64) {
    float v = red[tid] + red[tid + 64];
    v += __shfl_down(v, 32);
    v += __shfl_down(v, 16);
    v += __shfl_down(v, 8);
    v += __shfl_down(v, 4);
    v += __shfl_down(v, 2);
    v += __shfl_down(v, 1);
    if (tid == 0) red[0] = v;
  }
  __syncthreads();
  float scale = rsqrtf(red[0] * (1.f / 4096.f) + 1e-5f);
#pragma unroll
  for (int k = 0; k < 16; ++k) {
    int i = tid + k * 256;
    zbf[(long)t * 4096 + i] = f2bf(zv[k] * scale * nw[i]);
  }
}

// ---------- launch ----------
extern "C" void kernel_launch(void* const* d_in, const int* in_sizes, int n_in,
                              void* d_out, int out_size, void* d_ws, size_t ws_size,
                              hipStream_t stream) {
  const float* hidden = (const float*)d_in[0];
  const float* Win    = (const float*)d_in[1];
  const float* convw  = (const float*)d_in[2];
  const float* convb  = (const float*)d_in[3];
  const float* dtb    = (const float*)d_in[4];
  const float* Ap     = (const float*)d_in[5];
  const float* Dp     = (const float*)d_in[6];
  const float* nw     = (const float*)d_in[7];
  const float* Wout   = (const float*)d_in[8];
  float* out = (float*)d_out;
  char* ws = (char*)d_ws;

  // workspace layout (bytes)
  u16*   hb    = (u16*)(ws + 0);            //  8,388,608
  u16*   WinT  = (u16*)(ws + 8388608L);     // 35,127,296  [8576][2048] bf16
  u16*   pb    = (u16*)(ws + 43515904L);    // 33,554,432  [2048][8192] bf16 (gate+x)
  u16*   WoutT = (u16*)(ws + 113770496L);   // 16,777,216  [2048][4096] bf16
  u16*   xbf   = (u16*)(ws + 130547712L);   // 17,825,792  [2048][4352] bf16
  u16*   xT    = (u16*)(ws + 148373504L);   // 17,301,504  [4224][2048] bf16
  float* dt2   = (float*)(ws + 165675008L); //    524,288  [64][2048]
  float* cA2   = (float*)(ws + 166199296L); //    524,288  [64][2048]
  float* CBv   = (float*)(ws + 166723584L); //  2,097,152  [8][256][256]
  float* stT   = (float*)(ws + 168820736L); // 16,777,216  [8][64][128][64]
  u16*   prevT = (u16*)(ws + 185597952L);   //  8,388,608  [8][64][128][64] bf16
  u16*   zbf   = (u16*)(ws + 202375168L);   // 16,777,216  [2048][4096] bf16
  u16*   Y     = (u16*)(ws + 0);            // 16,777,216  bf16 (overlay hb+WinT, dead)
  float* Cp    = (float*)(ws + 43515904L);  // 67,108,864  out-proj partials x4 (overlay pb, dead post-rmsnorm)
  float* Cs    = (float*)(ws + 168820736L); // 12,582,912  strip partials x4 (overlay stT; consumed by conv+dt before states writes)

  cvt_bf16<<<4096, 256, 0, stream>>>(hidden, hb, 1048576);
  transpose_bf16<<<dim3(134, 32), 256, 0, stream>>>(Win, WinT, 2048, 8512);
  transpose_bf16<<<dim3(32, 64), 256, 0, stream>>>(Wout, WoutT, 4096, 2048);
  // in-proj main: gate+x cols [0,8192) -> pb bf16; 8x32 tiles of 256^2, 256 blocks
  gemm256<1><<<dim3(32, 8, 1), 512, 0, stream>>>(hb, WinT, pb, 8192, 2048, 2048, 0L);
  // in-proj strip: B/C/dt cols [8192,8576) f32, split-K4 (192 blocks of K=512)
  gemm_bt<<<dim3(3, 16, 4), 256, 0, stream>>>(hb, WinT + 8192L * 2048, Cs,
                                              384, 2048, 512, 786432L);
  conv_silu_t<<<dim3(136, 64), 256, 0, stream>>>(pb, Cs, convw, convb, xbf, xT);
  dt_cumsum<<<dim3(8, 64), 256, 0, stream>>>(Cs, dtb, Ap, dt2, cA2);
  cb_gemm<<<dim3(2, 2, 8), 256, 0, stream>>>(xbf, CBv);
  states_kernel<<<dim3(8, 64), 256, 0, stream>>>(xT, dt2, cA2, stT);
  scan_kernel<<<2048, 256, 0, stream>>>(stT, cA2, prevT);
  ssm_y_kernel<<<dim3(8, 64), 256, 0, stream>>>(xbf, xT, dt2, cA2, CBv, prevT, Dp, Y);
  rmsnorm_kernel<<<2048, 256, 0, stream>>>(Y, pb, nw, zbf);
  // out-proj: 8x8 tiles x split-K4 = 256 blocks, f32 partials + add4
  gemm256<0><<<dim3(8, 8, 4), 512, 0, stream>>>(zbf, WoutT, Cp, 2048, 4096, 1024, 4194304L);
  add4_kernel<<<4096, 256, 0, stream>>>(Cp, out);
}

// Round 10
// 383.808 us; speedup vs baseline: 1.1607x; 1.0094x over previous
//
#include <hip/hip_runtime.h>

// ---------- types ----------
typedef __bf16 bf16_t;
typedef bf16_t bf16x8 __attribute__((ext_vector_type(8)));
typedef float f32x4 __attribute__((ext_vector_type(4)));
typedef unsigned short u16;
typedef u16 u16x8 __attribute__((ext_vector_type(8)));
typedef u16 u16x4 __attribute__((ext_vector_type(4)));

// ---------- model dims ----------
#define SEQ   2048
#define HID   2048
#define INTER 4096
#define NH    64
#define HD    64
#define CONVD 4352
#define DIN   8512
#define CHNK  256
#define NC    8

__device__ __forceinline__ u16 f2bf(float f) {
  union { float f; unsigned u; } a; a.f = f;
  return (u16)((a.u + 0x7fffu + ((a.u >> 16) & 1u)) >> 16);
}
__device__ __forceinline__ float bf2f(u16 u) {
  union { unsigned u; float f; } a; a.u = ((unsigned)u) << 16;
  return a.f;
}

__device__ __forceinline__ void gl2lds16(const void* g, void* l) {
  auto gp = reinterpret_cast<__attribute__((address_space(1))) void*>(
      (unsigned long long)g);
  auto lp = reinterpret_cast<__attribute__((address_space(3))) void*>(
      (unsigned)(unsigned long long)l);
  __builtin_amdgcn_global_load_lds(gp, lp, 16, 0, 0);
}

// forced-register LDS vector read
__device__ __forceinline__ bf16x8 ds128(unsigned addr) {
  bf16x8 r;
  asm volatile("ds_read_b128 %0, %1" : "=v"(r) : "v"(addr));
  return r;
}

// ---------- fused prologue: hidden f32->bf16 + Win/Wout transpose->bf16 ----------
// blocks [0,4096): cvt; [4096,8384): Win T (134x32 of 64x64); [8384,10432): Wout T (32x64)
__global__ __launch_bounds__(256) void prep_fused(const float* __restrict__ hidden,
                                                  u16* __restrict__ hb,
                                                  const float* __restrict__ Win,
                                                  u16* __restrict__ WinT,
                                                  const float* __restrict__ Wout,
                                                  u16* __restrict__ WoutT) {
  __shared__ u16 t[64][72];
  const int b = blockIdx.x, tid = threadIdx.x;
  if (b < 4096) {
    int i = b * 256 + tid;
    f32x4 v = ((const f32x4*)hidden)[i];
    u16x4 r;
#pragma unroll
    for (int k = 0; k < 4; ++k) r[k] = f2bf(v[k]);
    ((u16x4*)hb)[i] = r;
    return;
  }
  const float* src; u16* dst; int R, Cc, n0, k0;
  if (b < 8384) {
    int idx = b - 4096;
    src = Win; dst = WinT; R = 2048; Cc = 8512;
    n0 = (idx % 134) * 64; k0 = (idx / 134) * 64;
  } else {
    int idx = b - 8384;
    src = Wout; dst = WoutT; R = 4096; Cc = 2048;
    n0 = (idx % 32) * 64; k0 = (idx / 32) * 64;
  }
  const int tx = tid & 15;   // n/4 group
  const int ty = tid >> 4;   // k row base
  if (n0 + 63 < Cc) {
#pragma unroll
    for (int j = 0; j < 4; ++j) {
      int k = ty + j * 16;
      f32x4 v = *(const f32x4*)(src + (long)(k0 + k) * Cc + n0 + tx * 4);
#pragma unroll
      for (int e = 0; e < 4; ++e) t[tx * 4 + e][k] = f2bf(v[e]);
    }
  } else {
#pragma unroll
    for (int j = 0; j < 4; ++j) {
      int k = ty + j * 16;
#pragma unroll
      for (int e = 0; e < 4; ++e) {
        int n = n0 + tx * 4 + e;
        t[tx * 4 + e][k] = (n < Cc) ? f2bf(src[(long)(k0 + k) * Cc + n]) : (u16)0;
      }
    }
  }
  __syncthreads();
  const int cg = tid & 7;
  const int r0 = tid >> 3;   // 0..31
#pragma unroll
  for (int j = 0; j < 2; ++j) {
    int row = r0 + j * 32;
    u16x8 o;
#pragma unroll
    for (int e = 0; e < 8; ++e) o[e] = t[row][cg * 8 + e];
    *(u16x8*)(dst + (long)(n0 + row) * R + k0 + cg * 8) = o;
  }
}

// ---------- bf16 MFMA GEMM: 128x128 tile, BK=64 (384-col strip, f32 out) ----------
__global__ __launch_bounds__(256, 2) void gemm_bt(const u16* __restrict__ A,
                                                  const u16* __restrict__ Bt,
                                                  float* __restrict__ C,
                                                  int N, int lda, int Klen,
                                                  long zstride) {
  __shared__ __align__(16) u16 As[128 * 64];
  __shared__ __align__(16) u16 Bs[128 * 64];
  const int kz = blockIdx.z;
  A  += (long)kz * Klen;
  Bt += (long)kz * Klen;
  C  += (long)kz * zstride;
  const int nb = gridDim.x * gridDim.y;
  const int id = blockIdx.x + gridDim.x * blockIdx.y;
  const int s = (id & 7) * (nb >> 3) + (id >> 3);
  const long bm = s & 15;
  const long bn = s >> 4;

  const int tid = threadIdx.x;
  const int lane = tid & 63;
  const int w = tid >> 6;
  const int wm = w >> 1, wn = w & 1;

  f32x4 acc[4][4];
#pragma unroll
  for (int i = 0; i < 4; ++i)
#pragma unroll
    for (int j = 0; j < 4; ++j) acc[i][j] = (f32x4){0.f, 0.f, 0.f, 0.f};

  const int srr = lane >> 3;
  const int sc8 = ((lane & 7) ^ srr) * 8;
  const u16* Agw = A + (bm * 128 + w * 8 + srr) * (long)lda + sc8;
  const u16* Bgw = Bt + (bn * 128 + w * 8 + srr) * (long)lda + sc8;
  u16* ldA = As + w * 512 + lane * 8;
  u16* ldB = Bs + w * 512 + lane * 8;
  const int fr = lane & 15, q = lane >> 4;
  const int fx = (fr & 7) << 3;

  for (int k0 = 0; k0 < Klen; k0 += 64) {
    __syncthreads();
#pragma unroll
    for (int t = 0; t < 4; ++t) {
      gl2lds16(Agw + k0 + (long)t * 32 * lda, ldA + t * 2048);
      gl2lds16(Bgw + k0 + (long)t * 32 * lda, ldB + t * 2048);
    }
    __builtin_amdgcn_s_waitcnt(0);
    __syncthreads();
#pragma unroll
    for (int ks = 0; ks < 2; ++ks) {
      bf16x8 af[4], bfv[4];
#pragma unroll
      for (int i = 0; i < 4; ++i)
        af[i] = *(const bf16x8*)(As + ((wm * 64 + i * 16 + fr) << 6) +
                                 ((((ks << 2) + q) << 3) ^ fx));
#pragma unroll
      for (int j = 0; j < 4; ++j)
        bfv[j] = *(const bf16x8*)(Bs + ((wn * 64 + j * 16 + fr) << 6) +
                                  ((((ks << 2) + q) << 3) ^ fx));
#pragma unroll
      for (int i = 0; i < 4; ++i)
#pragma unroll
        for (int j = 0; j < 4; ++j)
          acc[i][j] = __builtin_amdgcn_mfma_f32_16x16x32_bf16(af[i], bfv[j], acc[i][j], 0, 0, 0);
    }
  }
  const int cr = (lane >> 4) * 4;
  const int cc = lane & 15;
#pragma unroll
  for (int i = 0; i < 4; ++i)
#pragma unroll
    for (int j = 0; j < 4; ++j) {
      long r = bm * 128 + wm * 64 + i * 16 + cr;
      long cidx = bn * 128 + wn * 64 + j * 16 + cc;
      float* cp = C + r * (long)N + cidx;
#pragma unroll
      for (int t = 0; t < 4; ++t) cp[(long)t * N] = acc[i][j][t];
    }
}

// ============================================================================
// 256x256-tile 8-phase bf16 MFMA GEMM, BK=64, 512 threads (verified schedule).
// BFOUT=1 -> bf16 output, BFOUT=0 -> f32.
// ============================================================================
#define MFMA16(ACC, AF, BF)                                                    \
  _Pragma("unroll") for (int i_ = 0; i_ < 4; ++i_)                             \
  _Pragma("unroll") for (int j_ = 0; j_ < 2; ++j_) {                           \
    ACC[i_][j_] = __builtin_amdgcn_mfma_f32_16x16x32_bf16(                     \
        AF[i_][0], BF[j_][0], ACC[i_][j_], 0, 0, 0);                           \
    ACC[i_][j_] = __builtin_amdgcn_mfma_f32_16x16x32_bf16(                     \
        AF[i_][1], BF[j_][1], ACC[i_][j_], 0, 0, 0);                           \
  }

#define LDAF(DST, SLOT)                                                        \
  {                                                                            \
    unsigned ab_ = (unsigned)(unsigned long long)(&Abuf[SLOT][0]);             \
    _Pragma("unroll") for (int i_ = 0; i_ < 4; ++i_) {                         \
      unsigned ro_ = ab_ + (((wm * 64 + i_ * 16 + fr) << 6) << 1);             \
      DST[i_][0] = ds128(ro_ + (ke0 << 1));                                    \
      DST[i_][1] = ds128(ro_ + (ke1 << 1));                                    \
    }                                                                          \
  }

#define LDBF(DST, SLOT)                                                        \
  {                                                                            \
    unsigned bb_ = (unsigned)(unsigned long long)(&Bbuf[SLOT][0]);             \
    _Pragma("unroll") for (int j_ = 0; j_ < 2; ++j_) {                         \
      unsigned ro_ = bb_ + (((wn * 32 + j_ * 16 + fr) << 6) << 1);             \
      DST[j_][0] = ds128(ro_ + (ke0 << 1));                                    \
      DST[j_][1] = ds128(ro_ + (ke1 << 1));                                    \
    }                                                                          \
  }

#define STAGE(G, HO, KO, SLOT, BUF)                                            \
  {                                                                            \
    const u16* g_ = (G) + (HO) + (KO);                                         \
    gl2lds16(g_ + off1, BUF[SLOT] + lo1);                                      \
    gl2lds16(g_ + off2, BUF[SLOT] + lo2);                                      \
  }

#define PH_FENCE()                                                             \
  asm volatile("s_waitcnt lgkmcnt(0)" ::: "memory");                           \
  __builtin_amdgcn_sched_barrier(0);

template <int BFOUT>
__global__ __launch_bounds__(512, 2) void gemm256(const u16* __restrict__ A,
                                                  const u16* __restrict__ Bt,
                                                  void* __restrict__ Cv,
                                                  int N, int lda, int Klen,
                                                  long zstride) {
  __shared__ __align__(16) u16 Abuf[4][128 * 64];
  __shared__ __align__(16) u16 Bbuf[4][128 * 64];

  const int kz = blockIdx.z;
  A  += (long)kz * Klen;
  Bt += (long)kz * Klen;
  const long czoff = (long)kz * zstride;

  // XCD-contiguous remap (nb % 8 == 0)
  const int nb = gridDim.x * gridDim.y;
  const int id = blockIdx.x + gridDim.x * blockIdx.y;
  const int s = (id & 7) * (nb >> 3) + (id >> 3);
  const long bm = s & 7;
  const long bn = s >> 3;

  const int tid = threadIdx.x;
  const int lane = tid & 63;
  const int w = tid >> 6;        // wave 0..7
  const int wm = w >> 2;         // 0..1
  const int wn = w & 3;          // 0..3
  const int fr = lane & 15, q = lane >> 4;
  const int ke0 = (q ^ (fr & 7)) << 3;
  const int ke1 = ((4 + q) ^ (fr & 7)) << 3;

  const int sr1 = (w << 4) + (lane >> 3);
  const int sr2 = sr1 + 8;
  const int kcp = lane & 7;
  const long off1 = (long)sr1 * lda + ((kcp ^ (sr1 & 7)) << 3);
  const long off2 = (long)sr2 * lda + ((kcp ^ (sr2 & 7)) << 3);
  const int lo1 = (w << 10) + (lane << 3);
  const int lo2 = lo1 + 512;
  const long h128 = 128L * lda;

  const u16* gA = A + bm * 256 * lda;
  const u16* gB = Bt + bn * 256 * lda;

  f32x4 acc00[4][2], acc01[4][2], acc10[4][2], acc11[4][2];
#pragma unroll
  for (int i = 0; i < 4; ++i)
#pragma unroll
    for (int j = 0; j < 2; ++j) {
      acc00[i][j] = (f32x4){0.f, 0.f, 0.f, 0.f};
      acc01[i][j] = (f32x4){0.f, 0.f, 0.f, 0.f};
      acc10[i][j] = (f32x4){0.f, 0.f, 0.f, 0.f};
      acc11[i][j] = (f32x4){0.f, 0.f, 0.f, 0.f};
    }

  const int NT = Klen >> 6;

  // ---- prologue: stage tiles 0 and 1 fully ----
  STAGE(gA, 0L, 0L, 0, Abuf);
  STAGE(gB, 0L, 0L, 0, Bbuf);
  STAGE(gB, h128, 0L, 1, Bbuf);
  STAGE(gA, h128, 0L, 1, Abuf);
  STAGE(gA, 0L, 64L, 2, Abuf);
  STAGE(gB, 0L, 64L, 2, Bbuf);
  STAGE(gB, h128, 64L, 3, Bbuf);
  STAGE(gA, h128, 64L, 3, Abuf);
  asm volatile("s_waitcnt vmcnt(8)" ::: "memory");
  __builtin_amdgcn_s_barrier();

  for (int T = 0; T < NT; ++T) {
    const int t2 = (T << 1) & 3;
    const int t2p1 = (t2 + 1) & 3;
    const long kT2 = (long)(T + 2) << 6;
    const bool g2 = (T + 2 < NT);
    bf16x8 a0[4][2], a1[4][2], b0[2][2], b1[2][2];

    // ---- phase 1: quadrant (A0,B0) ----
    LDAF(a0, t2);
    LDBF(b0, t2);
    asm volatile("s_waitcnt lgkmcnt(8)" ::: "memory");
    __builtin_amdgcn_s_barrier();
    PH_FENCE();
    __builtin_amdgcn_s_setprio(1);
    MFMA16(acc00, a0, b0);
    __builtin_amdgcn_s_setprio(0);
    __builtin_amdgcn_s_barrier();

    // ---- phase 2: quadrant (A0,B1); stage A0(T+2) ----
    LDBF(b1, t2p1);
    if (g2) STAGE(gA, 0L, kT2, t2, Abuf);
    __builtin_amdgcn_s_barrier();
    PH_FENCE();
    __builtin_amdgcn_s_setprio(1);
    MFMA16(acc01, a0, b1);
    __builtin_amdgcn_s_setprio(0);
    __builtin_amdgcn_s_barrier();

    // ---- phase 3: quadrant (A1,B0); stage B0(T+2) ----
    LDAF(a1, t2p1);
    if (g2) STAGE(gB, 0L, kT2, t2, Bbuf);
    __builtin_amdgcn_s_barrier();
    PH_FENCE();
    __builtin_amdgcn_s_setprio(1);
    MFMA16(acc10, a1, b0);
    __builtin_amdgcn_s_setprio(0);
    __builtin_amdgcn_s_barrier();

    // ---- phase 4: quadrant (A1,B1); stage B1+A1(T+2); single wait ----
    if (g2) {
      STAGE(gB, h128, kT2, t2p1, Bbuf);
      STAGE(gA, h128, kT2, t2p1, Abuf);
    }
    __builtin_amdgcn_s_barrier();
    PH_FENCE();
    __builtin_amdgcn_s_setprio(1);
    MFMA16(acc11, a1, b1);
    __builtin_amdgcn_s_setprio(0);
    if (g2)
      asm volatile("s_waitcnt vmcnt(8)" ::: "memory");
    else
      asm volatile("s_waitcnt vmcnt(0)" ::: "memory");
    __builtin_amdgcn_s_barrier();
  }

  // ---- epilogue: C write, col-guarded; bf16 or f32 per BFOUT ----
  const int cr = (lane >> 4) << 2;
  const int cc = lane & 15;
  const long r0 = bm * 256 + wm * 64 + cr;
  const long c0 = bn * 256 + wn * 32 + cc;
#define CWRITE(ACC, QA, QB)                                                    \
  _Pragma("unroll") for (int i_ = 0; i_ < 4; ++i_)                             \
  _Pragma("unroll") for (int j_ = 0; j_ < 2; ++j_) {                           \
    long r_ = r0 + (QA)*128 + i_ * 16;                                         \
    long c_ = c0 + (QB)*128 + j_ * 16;                                         \
    if (c_ < N) {                                                              \
      long base_ = czoff + r_ * (long)N + c_;                                  \
      _Pragma("unroll") for (int t_ = 0; t_ < 4; ++t_) {                       \
        if (BFOUT)                                                             \
          ((u16*)Cv)[base_ + (long)t_ * N] = f2bf(ACC[i_][j_][t_]);            \
        else                                                                   \
          ((float*)Cv)[base_ + (long)t_ * N] = ACC[i_][j_][t_];                \
      }                                                                        \
    }                                                                          \
  }
  CWRITE(acc00, 0, 0)
  CWRITE(acc01, 0, 1)
  CWRITE(acc10, 1, 0)
  CWRITE(acc11, 1, 1)
#undef CWRITE
}

// ---------- split-K-4 partial add: out = p0+p1+p2+p3 (compact [2048][4096]) ----------
__global__ __launch_bounds__(256) void add4_kernel(const float* __restrict__ a,
                                                   float* __restrict__ o) {
  int i = blockIdx.x * 256 + threadIdx.x;
  f32x4 r = ((const f32x4*)a)[i];
  r += ((const f32x4*)(a + 4194304L))[i];
  r += ((const f32x4*)(a + 8388608L))[i];
  r += ((const f32x4*)(a + 12582912L))[i];
  ((f32x4*)o)[i] = r;
}

// ---------- fused depthwise conv (K=4) + SiLU -> xbf AND xT (transposed) ----------
// x region (cols<4096) read from bf16 pb; B/C region summed from 4 strip partials.
__global__ __launch_bounds__(256) void conv_silu_t(const u16* __restrict__ pb,
                                                   const float* __restrict__ Cs,
                                                   const float* __restrict__ cw,
                                                   const float* __restrict__ cb,
                                                   u16* __restrict__ xbf,
                                                   u16* __restrict__ xT) {
  __shared__ float ld[35][33];
  __shared__ u16 tt[32][34];
  const int c0 = blockIdx.x * 32, t0 = blockIdx.y * 32;
  const int tx = threadIdx.x & 31, ty = threadIdx.x >> 5;
  const bool mainreg = (c0 < 4096);
  for (int i = ty; i < 35; i += 8) {
    int t = t0 - 3 + i;
    float v = 0.f;
    if (t >= 0) {
      if (mainreg) {
        v = bf2f(pb[(long)t * 8192 + 4096 + c0 + tx]);
      } else {
        long idx = (long)t * 384 + (c0 - 4096) + tx;
        v = Cs[idx];
        v += Cs[idx + 786432L];
        v += Cs[idx + 1572864L];
        v += Cs[idx + 2359296L];
      }
    }
    ld[i][tx] = v;
  }
  const int c = c0 + tx;
  const float w0 = cw[c * 4 + 0], w1 = cw[c * 4 + 1], w2 = cw[c * 4 + 2],
              w3 = cw[c * 4 + 3], bias = cb[c];
  __syncthreads();
  for (int i = ty; i < 32; i += 8) {
    float a = bias + w0 * ld[i][tx] + w1 * ld[i + 1][tx] + w2 * ld[i + 2][tx] +
              w3 * ld[i + 3][tx];
    u16 v = f2bf(a / (1.f + __expf(-a)));
    xbf[(long)(t0 + i) * CONVD + c] = v;
    tt[i][tx] = v;
  }
  __syncthreads();
  if (c0 < 4224) {   // x + B + C regions get transposed
    for (int i = ty; i < 32; i += 8)
      xT[(long)(c0 + i) * 2048 + t0 + tx] = tt[tx][i];
  }
}

// ---------- dt softplus + per-chunk cumsum (Hillis-Steele), [h][t] layout ----------
__global__ __launch_bounds__(256) void dt_cumsum(const float* __restrict__ Cs,
                                                 const float* __restrict__ dtb,
                                                 const float* __restrict__ A,
                                                 float* __restrict__ dt2,
                                                 float* __restrict__ cA2) {
  __shared__ float sc[256];
  int c = blockIdx.x, h = blockIdx.y, l = threadIdx.x;
  long idx = (long)(c * 256 + l) * 384 + 256 + h;
  float v = Cs[idx];
  v += Cs[idx + 786432L];
  v += Cs[idx + 1572864L];
  v += Cs[idx + 2359296L];
  v += dtb[h];
  float sp = (v > 20.f) ? v : log1pf(__expf(v));
  dt2[h * 2048 + c * 256 + l] = sp;
  sc[l] = sp * A[h];
  __syncthreads();
  for (int off = 1; off < 256; off <<= 1) {
    float t = (l >= off) ? sc[l - off] : 0.f;
    __syncthreads();
    sc[l] += t;
    __syncthreads();
  }
  cA2[h * 2048 + c * 256 + l] = sc[l];
}

// ---------- CB[c][l][s] = C[l,:].B[s,:] via MFMA, per-chunk strided GEMM ----------
__global__ __launch_bounds__(256, 2) void cb_gemm(const u16* __restrict__ xbf,
                                                  float* __restrict__ CB) {
  __shared__ __align__(16) u16 As[128 * 32];
  __shared__ __align__(16) u16 Bs[128 * 32];
  const int tid = threadIdx.x;
  const int lane = tid & 63;
  const int w = tid >> 6;
  const int wm = w >> 1, wn = w & 1;
  const int bm = blockIdx.y, bn = blockIdx.x, c = blockIdx.z;

  f32x4 acc[4][4];
#pragma unroll
  for (int i = 0; i < 4; ++i)
#pragma unroll
    for (int j = 0; j < 4; ++j) acc[i][j] = (f32x4){0.f, 0.f, 0.f, 0.f};

  const int sr = w * 32 + (lane >> 2);
  const int sc = ((lane & 3) ^ ((lane >> 2) & 3)) * 8;
  const u16* Ag = xbf + (long)(c * 256 + bm * 128) * CONVD + 4224;  // C region
  const u16* Bg = xbf + (long)(c * 256 + bn * 128) * CONVD + 4096;  // B region
  u16* lA0 = As + w * 1024 + lane * 8;
  u16* lA1 = As + w * 1024 + 512 + lane * 8;
  u16* lB0 = Bs + w * 1024 + lane * 8;
  u16* lB1 = Bs + w * 1024 + 512 + lane * 8;
  const int fr = lane & 15, q = lane >> 4;
  const int pc = ((q ^ (fr & 3)) << 3);

  for (int k0 = 0; k0 < 128; k0 += 32) {
    __syncthreads();
    const u16* a0 = Ag + (long)sr * CONVD + k0 + sc;
    const u16* b0 = Bg + (long)sr * CONVD + k0 + sc;
    gl2lds16(a0, lA0);
    gl2lds16(a0 + 16L * CONVD, lA1);
    gl2lds16(b0, lB0);
    gl2lds16(b0 + 16L * CONVD, lB1);
    __builtin_amdgcn_s_waitcnt(0);
    __syncthreads();
    bf16x8 af[4], bfv[4];
#pragma unroll
    for (int i = 0; i < 4; ++i)
      af[i] = *(const bf16x8*)(As + ((wm * 64 + i * 16 + fr) << 5) + pc);
#pragma unroll
    for (int j = 0; j < 4; ++j)
      bfv[j] = *(const bf16x8*)(Bs + ((wn * 64 + j * 16 + fr) << 5) + pc);
#pragma unroll
    for (int i = 0; i < 4; ++i)
#pragma unroll
      for (int j = 0; j < 4; ++j)
        acc[i][j] = __builtin_amdgcn_mfma_f32_16x16x32_bf16(af[i], bfv[j], acc[i][j], 0, 0, 0);
  }
  const int cr = (lane >> 4) * 4;
  const int cc = lane & 15;
  float* Cc = CB + (long)c * 65536;
#pragma unroll
  for (int i = 0; i < 4; ++i)
#pragma unroll
    for (int j = 0; j < 4; ++j) {
      int r = bm * 128 + wm * 64 + i * 16 + cr;
      int cidx = bn * 128 + wn * 64 + j * 16 + cc;
      float* cp = Cc + (long)r * 256 + cidx;
#pragma unroll
      for (int t = 0; t < 4; ++t) cp[t * 256] = acc[i][j][t];
    }
}

// ---------- states via MFMA: stT[n][p] = sum_l (B[l][n]*wl[l]) * x[l][p] ----------
#define LDM 72
__global__ __launch_bounds__(256) void states_kernel(const u16* __restrict__ xT,
                                                     const float* __restrict__ dt2,
                                                     const float* __restrict__ cA2,
                                                     float* __restrict__ stT) {
  __shared__ __align__(16) u16 Ms[128 * LDM];  // Bw [n][l_local]
  __shared__ __align__(16) u16 Xs[64 * LDM];   // x  [p][l_local]
  __shared__ float wl[256];
  const int c = blockIdx.x, h = blockIdx.y;
  const int tid = threadIdx.x;
  const int lane = tid & 63, w = tid >> 6;
  const int fr = lane & 15, q = lane >> 4;
  {
    float calast = cA2[h * 2048 + c * 256 + 255];
    float ca = cA2[h * 2048 + c * 256 + tid];
    wl[tid] = __expf(calast - ca) * dt2[h * 2048 + c * 256 + tid];
  }
  f32x4 acc[2][4];
#pragma unroll
  for (int i = 0; i < 2; ++i)
#pragma unroll
    for (int j = 0; j < 4; ++j) acc[i][j] = (f32x4){0.f, 0.f, 0.f, 0.f};

  const int lc8 = (tid & 7) * 8;
  const int rn = tid >> 3;   // 0..31
  __syncthreads();

  for (int kt = 0; kt < 4; ++kt) {
    __syncthreads();
#pragma unroll
    for (int r = 0; r < 4; ++r) {
      int n = rn + 32 * r;
      u16x8 raw = *(const u16x8*)(xT + (long)(4096 + n) * 2048 + c * 256 + kt * 64 + lc8);
      union { u16 u[8]; bf16x8 v; } pk;
#pragma unroll
      for (int u = 0; u < 8; ++u)
        pk.u[u] = f2bf(bf2f(raw[u]) * wl[kt * 64 + lc8 + u]);
      *(bf16x8*)(Ms + n * LDM + lc8) = pk.v;
    }
#pragma unroll
    for (int r = 0; r < 2; ++r) {
      int p = rn + 32 * r;
      *(bf16x8*)(Xs + p * LDM + lc8) =
          *(const bf16x8*)(xT + (long)(h * 64 + p) * 2048 + c * 256 + kt * 64 + lc8);
    }
    __syncthreads();
#pragma unroll
    for (int ks = 0; ks < 64; ks += 32) {
      bf16x8 af[2], xf[4];
#pragma unroll
      for (int i = 0; i < 2; ++i)
        af[i] = *(const bf16x8*)(Ms + (w * 32 + i * 16 + fr) * LDM + ks + q * 8);
#pragma unroll
      for (int j = 0; j < 4; ++j)
        xf[j] = *(const bf16x8*)(Xs + (j * 16 + fr) * LDM + ks + q * 8);
#pragma unroll
      for (int i = 0; i < 2; ++i)
#pragma unroll
        for (int j = 0; j < 4; ++j)
          acc[i][j] = __builtin_amdgcn_mfma_f32_16x16x32_bf16(af[i], xf[j], acc[i][j], 0, 0, 0);
    }
  }
  const int cr = (lane >> 4) * 4;
  const int cc = lane & 15;
  float* outp = stT + (long)(c * 64 + h) * 8192;
#pragma unroll
  for (int i = 0; i < 2; ++i)
#pragma unroll
    for (int j = 0; j < 4; ++j) {
      int n = w * 32 + i * 16 + cr;
      int p = j * 16 + cc;
#pragma unroll
      for (int t = 0; t < 4; ++t) outp[(n + t) * 64 + p] = acc[i][j][t];
    }
}

// ---------- 8-chunk inter-chunk scan (vectorized x4; bf16 prevT out) ----------
__global__ __launch_bounds__(256) void scan_kernel(const float* __restrict__ stT,
                                                   const float* __restrict__ cA2,
                                                   u16* __restrict__ prevT) {
  int g = blockIdx.x * 256 + threadIdx.x;   // f32x4 group: h*2048 + (n*64+p)/4
  int h = g >> 11;
  f32x4 acc = (f32x4){0.f, 0.f, 0.f, 0.f};
#pragma unroll
  for (int c = 0; c < NC; ++c) {
    u16x4 o;
#pragma unroll
    for (int e = 0; e < 4; ++e) o[e] = f2bf(acc[e]);
    ((u16x4*)(prevT + (long)c * 524288))[g] = o;
    float cd = __expf(cA2[h * 2048 + c * 256 + 255]);
    f32x4 st = ((const f32x4*)(stT + (long)c * 524288))[g];
    acc = acc * cd + st;
  }
}

// ---------- intra+inter SSM output via bf16 MFMA ----------
__global__ __launch_bounds__(256) void ssm_y_kernel(const u16* __restrict__ xbf,
                                                    const u16* __restrict__ xT,
                                                    const float* __restrict__ dt2,
                                                    const float* __restrict__ cA2,
                                                    const float* __restrict__ CB,
                                                    const u16* __restrict__ prevT,
                                                    const float* __restrict__ Dp,
                                                    u16* __restrict__ Y) {
  __shared__ __align__(16) u16 Ms[256 * LDM];
  __shared__ __align__(16) u16 Xt[64 * LDM];
  __shared__ float cas[256];
  __shared__ float dts[256];
  const int c = blockIdx.x, h = blockIdx.y;
  const int tid = threadIdx.x;
  const int lane = tid & 63;
  const int w = tid >> 6;
  const int fr = lane & 15, q = lane >> 4;

  cas[tid] = cA2[h * 2048 + c * 256 + tid];
  dts[tid] = dt2[h * 2048 + c * 256 + tid];

  f32x4 acc[4][4];
#pragma unroll
  for (int i = 0; i < 4; ++i)
#pragma unroll
    for (int j = 0; j < 4; ++j) acc[i][j] = (f32x4){0.f, 0.f, 0.f, 0.f};

  const int sg = (tid & 7) * 8;
  const int lb = tid >> 3;
  const int xp = tid & 63;
  const int xq = tid >> 6;

  __syncthreads();

  for (int kt = 0; kt < 6; ++kt) {
    __syncthreads();
    if (kt < 4) {
      const int s0 = kt * 64;
      f32x4 e0 = *(const f32x4*)&cas[s0 + sg];
      f32x4 e1 = *(const f32x4*)&cas[s0 + sg + 4];
      f32x4 d0 = *(const f32x4*)&dts[s0 + sg];
      f32x4 d1 = *(const f32x4*)&dts[s0 + sg + 4];
#pragma unroll
      for (int k = 0; k < 8; ++k) {
        const int l = lb + 32 * k;
        const float cal = cas[l];
        const float* cb = CB + (long)c * 65536 + (long)l * 256 + s0 + sg;
        f32x4 c0 = *(const f32x4*)cb;
        f32x4 c1 = *(const f32x4*)(cb + 4);
        union { u16 u[8]; bf16x8 v; } pk;
#pragma unroll
        for (int u = 0; u < 8; ++u) {
          int s = s0 + sg + u;
          float cv = (u < 4) ? c0[u] : c1[u - 4];
          float cs = (u < 4) ? e0[u] : e1[u - 4];
          float dv = (u < 4) ? d0[u] : d1[u - 4];
          float m = (s <= l) ? cv * __expf(cal - cs) * dv : 0.f;
          pk.u[u] = f2bf(m);
        }
        *(bf16x8*)(Ms + l * LDM + sg) = pk.v;
      }
#pragma unroll
      for (int r = 0; r < 2; ++r) {
        int p = (tid >> 3) + 32 * r;
        *(bf16x8*)(Xt + p * LDM + sg) =
            *(const bf16x8*)(xT + (long)(h * 64 + p) * 2048 + c * 256 + s0 + sg);
      }
    } else {
      const int n0 = (kt - 4) * 64;
#pragma unroll
      for (int k = 0; k < 8; ++k) {
        const int l = lb + 32 * k;
        const float ea = __expf(cas[l]);
        u16x8 raw = *(const u16x8*)(xbf + (long)(c * 256 + l) * CONVD + 4224 + n0 + sg);
        union { u16 u[8]; bf16x8 v; } pk;
#pragma unroll
        for (int u = 0; u < 8; ++u) pk.u[u] = f2bf(ea * bf2f(raw[u]));
        *(bf16x8*)(Ms + l * LDM + sg) = pk.v;
      }
      const u16* pT = prevT + (long)(c * 64 + h) * 8192;
#pragma unroll
      for (int half = 0; half < 2; ++half) {
        const int nb2 = xq * 16 + half * 8;
        union { u16 u[8]; bf16x8 v; } pk;
#pragma unroll
        for (int u = 0; u < 8; ++u) pk.u[u] = pT[(n0 + nb2 + u) * 64 + xp];
        *(bf16x8*)(Xt + xp * LDM + nb2) = pk.v;
      }
    }
    __syncthreads();
#pragma unroll
    for (int ks = 0; ks < 64; ks += 32) {
      bf16x8 af[4], bfv[4];
#pragma unroll
      for (int i = 0; i < 4; ++i)
        af[i] = *(const bf16x8*)(Ms + (w * 64 + i * 16 + fr) * LDM + ks + q * 8);
#pragma unroll
      for (int j = 0; j < 4; ++j)
        bfv[j] = *(const bf16x8*)(Xt + (j * 16 + fr) * LDM + ks + q * 8);
#pragma unroll
      for (int i = 0; i < 4; ++i)
#pragma unroll
        for (int j = 0; j < 4; ++j)
          acc[i][j] = __builtin_amdgcn_mfma_f32_16x16x32_bf16(af[i], bfv[j], acc[i][j], 0, 0, 0);
    }
  }

  const int cr = (lane >> 4) * 4;
  const int cc = lane & 15;
  const float dh = Dp[h];
#pragma unroll
  for (int i = 0; i < 4; ++i)
#pragma unroll
    for (int j = 0; j < 4; ++j) {
      const int p = j * 16 + cc;
#pragma unroll
      for (int t = 0; t < 4; ++t) {
        const int row = w * 64 + i * 16 + cr + t;
        const float xv = bf2f(xbf[(long)(c * 256 + row) * CONVD + h * 64 + p]);
        Y[(long)(c * 256 + row) * 4096 + h * 64 + p] = f2bf(acc[i][j][t] + dh * xv);
      }
    }
}

// ---------- gated RMSNorm (Y bf16, gate bf16 from pb) -> bf16 z, vectorized ----------
__global__ __launch_bounds__(256) void rmsnorm_kernel(const u16* __restrict__ Y,
                                                      const u16* __restrict__ pb,
                                                      const float* __restrict__ nw,
                                                      u16* __restrict__ zbf) {
  __shared__ float red[256];
  int t = blockIdx.x, tid = threadIdx.x;
  const u16* y = Y + (long)t * 4096 + tid * 16;
  const u16* g = pb + (long)t * 8192 + tid * 16;
  u16x8 yv0 = *(const u16x8*)y;
  u16x8 yv1 = *(const u16x8*)(y + 8);
  u16x8 gv0 = *(const u16x8*)g;
  u16x8 gv1 = *(const u16x8*)(g + 8);
  float zv[16];
  float s = 0.f;
#pragma unroll
  for (int e = 0; e < 8; ++e) {
    float gv = bf2f(gv0[e]);
    float z = bf2f(yv0[e]) * (gv / (1.f + __expf(-gv)));
    zv[e] = z;
    s += z * z;
  }
#pragma unroll
  for (int e = 0; e < 8; ++e) {
    float gv = bf2f(gv1[e]);
    float z = bf2f(yv1[e]) * (gv / (1.f + __expf(-gv)));
    zv[8 + e] = z;
    s += z * z;
  }
  red[tid] = s;
  __syncthreads();
  if (tid < 128) red[tid] += red[tid + 128];
  __syncthreads();
  if (tid < 64) {
    float v = red[tid] + red[tid + 64];
    v += __shfl_down(v, 32);
    v += __shfl_down(v, 16);
    v += __shfl_down(v, 8);
    v += __shfl_down(v, 4);
    v += __shfl_down(v, 2);
    v += __shfl_down(v, 1);
    if (tid == 0) red[0] = v;
  }
  __syncthreads();
  float scale = rsqrtf(red[0] * (1.f / 4096.f) + 1e-5f);
  const float* wp = nw + tid * 16;
  f32x4 w0 = ((const f32x4*)wp)[0], w1 = ((const f32x4*)wp)[1];
  f32x4 w2 = ((const f32x4*)wp)[2], w3 = ((const f32x4*)wp)[3];
  u16x8 o0, o1;
#pragma unroll
  for (int e = 0; e < 4; ++e) {
    o0[e]     = f2bf(zv[e]      * scale * w0[e]);
    o0[4 + e] = f2bf(zv[4 + e]  * scale * w1[e]);
    o1[e]     = f2bf(zv[8 + e]  * scale * w2[e]);
    o1[4 + e] = f2bf(zv[12 + e] * scale * w3[e]);
  }
  u16* zp = zbf + (long)t * 4096 + tid * 16;
  *(u16x8*)zp = o0;
  *(u16x8*)(zp + 8) = o1;
}

// ---------- launch ----------
extern "C" void kernel_launch(void* const* d_in, const int* in_sizes, int n_in,
                              void* d_out, int out_size, void* d_ws, size_t ws_size,
                              hipStream_t stream) {
  const float* hidden = (const float*)d_in[0];
  const float* Win    = (const float*)d_in[1];
  const float* convw  = (const float*)d_in[2];
  const float* convb  = (const float*)d_in[3];
  const float* dtb    = (const float*)d_in[4];
  const float* Ap     = (const float*)d_in[5];
  const float* Dp     = (const float*)d_in[6];
  const float* nw     = (const float*)d_in[7];
  const float* Wout   = (const float*)d_in[8];
  float* out = (float*)d_out;
  char* ws = (char*)d_ws;

  // workspace layout (bytes)
  u16*   hb    = (u16*)(ws + 0);            //  8,388,608
  u16*   WinT  = (u16*)(ws + 8388608L);     // 35,127,296  [8576][2048] bf16
  u16*   pb    = (u16*)(ws + 43515904L);    // 33,554,432  [2048][8192] bf16 (gate+x)
  u16*   WoutT = (u16*)(ws + 113770496L);   // 16,777,216  [2048][4096] bf16
  u16*   xbf   = (u16*)(ws + 130547712L);   // 17,825,792  [2048][4352] bf16
  u16*   xT    = (u16*)(ws + 148373504L);   // 17,301,504  [4224][2048] bf16
  float* dt2   = (float*)(ws + 165675008L); //    524,288  [64][2048]
  float* cA2   = (float*)(ws + 166199296L); //    524,288  [64][2048]
  float* CBv   = (float*)(ws + 166723584L); //  2,097,152  [8][256][256]
  float* stT   = (float*)(ws + 168820736L); // 16,777,216  [8][64][128][64]
  u16*   prevT = (u16*)(ws + 185597952L);   //  8,388,608  [8][64][128][64] bf16
  u16*   zbf   = (u16*)(ws + 202375168L);   // 16,777,216  [2048][4096] bf16
  u16*   Y     = (u16*)(ws + 0);            // 16,777,216  bf16 (overlay hb+WinT, dead)
  float* Cp    = (float*)(ws + 43515904L);  // 67,108,864  out-proj partials x4 (overlay pb, dead post-rmsnorm)
  float* Cs    = (float*)(ws + 168820736L); // 12,582,912  strip partials x4 (overlay stT; consumed by conv+dt before states writes)

  // fused prologue: cvt (4096) + Win T (4288) + Wout T (2048) blocks
  prep_fused<<<10432, 256, 0, stream>>>(hidden, hb, Win, WinT, Wout, WoutT);
  // in-proj main: gate+x cols [0,8192) -> pb bf16; 8x32 tiles of 256^2, 256 blocks
  gemm256<1><<<dim3(32, 8, 1), 512, 0, stream>>>(hb, WinT, pb, 8192, 2048, 2048, 0L);
  // in-proj strip: B/C/dt cols [8192,8576) f32, split-K4 (192 blocks of K=512)
  gemm_bt<<<dim3(3, 16, 4), 256, 0, stream>>>(hb, WinT + 8192L * 2048, Cs,
                                              384, 2048, 512, 786432L);
  conv_silu_t<<<dim3(136, 64), 256, 0, stream>>>(pb, Cs, convw, convb, xbf, xT);
  dt_cumsum<<<dim3(8, 64), 256, 0, stream>>>(Cs, dtb, Ap, dt2, cA2);
  cb_gemm<<<dim3(2, 2, 8), 256, 0, stream>>>(xbf, CBv);
  states_kernel<<<dim3(8, 64), 256, 0, stream>>>(xT, dt2, cA2, stT);
  scan_kernel<<<512, 256, 0, stream>>>(stT, cA2, prevT);
  ssm_y_kernel<<<dim3(8, 64), 256, 0, stream>>>(xbf, xT, dt2, cA2, CBv, prevT, Dp, Y);
  rmsnorm_kernel<<<2048, 256, 0, stream>>>(Y, pb, nw, zbf);
  // out-proj: 8x8 tiles x split-K4 = 256 blocks, f32 partials + add4
  gemm256<0><<<dim3(8, 8, 4), 512, 0, stream>>>(zbf, WoutT, Cp, 2048, 4096, 1024, 4194304L);
  add4_kernel<<<4096, 256, 0, stream>>>(Cp, out);
}